// Round 12
// baseline (436.757 us; speedup 1.0000x reference)
//
#include <hip/hip_runtime.h>

// SiameseGNN round 12: aggregate geometry 8x8 -> 4x16 (butterfly 3->2 levels).
//
// R11 evidence: k_agg2 85.6us, VALUBusy 71%, FETCH 171MB, gather instrs at
// ~131 cyc/instr slack -> VALU-bound. Per-node op budget ~95, of which ~36
// is the 3-level cross-group butterfly (4 float2 accs). Fix: 4 edge-groups
// x 16 lanes x uint2 (8B) -- same 128B row coverage, same unpack work, but
// 2 accs and a 2-level butterfly (12 ops), cheaper remainder. VMEM instr
// count doubles into measured slack. Everything else unchanged from R11.

#define TPB    256
#define CHUNK  128
#define SHIFT  7
#define KMAX   1024
#define CAP    2560
#define EPB    4096

typedef __attribute__((ext_vector_type(8))) short short8;
typedef __attribute__((ext_vector_type(4))) float f32x4;
typedef __attribute__((ext_vector_type(2))) float float2v;

struct Ctx {
    const float* X; const int* esrc; const int* edst;
    unsigned int* temp; unsigned short* Ab; unsigned short* Hs;
    int* csr; int* row_ptr; float* dinv; int* cursorG; int* bucketBase;
    float* P; float* P2; float* outp;
};

__device__ __forceinline__ float bf2f(unsigned short u) {
    union { unsigned int i; float f; } c; c.i = ((unsigned int)u) << 16; return c.f;
}
__device__ __forceinline__ unsigned short f2bf(float x) {
    union { float f; unsigned int i; } c; c.f = x;
    unsigned int r = c.i + 0x7FFFu + ((c.i >> 16) & 1u);   // RNE
    return (unsigned short)(r >> 16);
}
// unpack bf16 pair (one dword) -> float2 {low, high}
__device__ __forceinline__ float2v up2(unsigned int w) {
    union { unsigned int i; float f; } lo, hi;
    lo.i = w << 16; hi.i = w & 0xFFFF0000u;
    float2v r; r.x = lo.f; r.y = hi.f; return r;
}

__global__ void k_prepW2(const float* __restrict__ W1, const float* __restrict__ W2,
                         unsigned short* __restrict__ Wt1, unsigned short* __restrict__ Wt2) {
    const float* W = blockIdx.x ? W2 : W1;
    unsigned short* Wt = blockIdx.x ? Wt2 : Wt1;
    for (int i = threadIdx.x; i < 64 * 64; i += 256) {
        int n = i >> 6, k = i & 63;
        Wt[i] = f2bf(W[k * 64 + n]);
    }
}

__global__ void k_zeroCur(Ctx c0, Ctx c1, int nb0, int K) {
    int b = blockIdx.x; Ctx c = c0;
    if (b >= nb0) { c = c1; b -= nb0; }
    int i = b * blockDim.x + threadIdx.x;
    if (i < K) c.cursorG[i] = 0;
}

// Bucket edges by dst (packed (dstLocal<<17)|src) -- contiguous segment writes.
__global__ __launch_bounds__(256) void k_binA(Ctx c0, Ctx c1, int nb0, int E, int K) {
    __shared__ int cnt[KMAX];
    __shared__ int segBase[KMAX];
    int b = blockIdx.x; Ctx c = c0;
    if (b >= nb0) { c = c1; b -= nb0; }
    int tid = threadIdx.x;
    for (int j = tid; j < K; j += 256) cnt[j] = 0;
    __syncthreads();
    int base = b * EPB;
#pragma unroll
    for (int k = 0; k < EPB / 256; ++k) {
        int e = base + k * 256 + tid;
        if (e < E) atomicAdd(&cnt[c.edst[e] >> SHIFT], 1);
    }
    __syncthreads();
    for (int j = tid; j < K; j += 256) {
        int cc = cnt[j];
        segBase[j] = cc ? atomicAdd(&c.cursorG[j], cc) : 0;
        cnt[j] = 0;
    }
    __syncthreads();
#pragma unroll
    for (int k = 0; k < EPB / 256; ++k) {
        int e = base + k * 256 + tid;
        if (e < E) {
            int d = c.edst[e];
            int bk = d >> SHIFT;
            int pos = segBase[bk] + atomicAdd(&cnt[bk], 1);
            if (pos < CAP)
                c.temp[(size_t)bk * CAP + pos] =
                    ((unsigned int)(d & (CHUNK - 1)) << 17) | (unsigned int)c.esrc[e];
        }
    }
}

__global__ __launch_bounds__(1024) void k_scanK(Ctx c0, Ctx c1, int K, int N, int E) {
    Ctx c = blockIdx.x ? c1 : c0;
    __shared__ int s[1024];
    int tid = threadIdx.x;
    int v = (tid < K) ? c.cursorG[tid] : 0;
    s[tid] = v;
    __syncthreads();
#pragma unroll
    for (int off = 1; off < 1024; off <<= 1) {
        int t = (tid >= off) ? s[tid - off] : 0;
        __syncthreads();
        s[tid] += t;
        __syncthreads();
    }
    if (tid < K) c.bucketBase[tid] = s[tid] - v;
    if (tid == 0) c.row_ptr[N] = E;
}

// Per-bucket LDS counting sort -> contiguous csr slice + row_ptr + dinv.
__global__ __launch_bounds__(256) void k_csrb(Ctx c0, Ctx c1, int nb0, int N) {
    __shared__ int deg[CHUNK];
    __shared__ int lofs[CHUNK];
    __shared__ int cur[CHUNK];
    int b = blockIdx.x; Ctx c = c0;
    if (b >= nb0) { c = c1; b -= nb0; }
    int tid = threadIdx.x;
    if (tid < CHUNK) deg[tid] = 0;
    __syncthreads();
    int cnt = c.cursorG[b]; if (cnt > CAP) cnt = CAP;
    const size_t tb = (size_t)b * CAP;
    for (int i = tid; i < cnt; i += 256) atomicAdd(&deg[c.temp[tb + i] >> 17], 1);
    __syncthreads();
    if (tid < CHUNK) lofs[tid] = deg[tid];
    __syncthreads();
#pragma unroll
    for (int off = 1; off < CHUNK; off <<= 1) {
        int t = (tid < CHUNK && tid >= off) ? lofs[tid - off] : 0;
        __syncthreads();
        if (tid < CHUNK) lofs[tid] += t;
        __syncthreads();
    }
    int base = c.bucketBase[b];
    if (tid < CHUNK) {
        int excl = lofs[tid] - deg[tid];
        lofs[tid] = excl;
        cur[tid] = 0;
        int node = b * CHUNK + tid;
        if (node < N) {
            c.row_ptr[node] = base + excl;
            c.dinv[node] = rsqrtf((float)deg[tid] + 1.0f);
        }
    }
    __syncthreads();
    for (int i = tid; i < cnt; i += 256) {
        unsigned int p = c.temp[tb + i];
        int dl = p >> 17;
        int rank = atomicAdd(&cur[dl], 1);
        c.csr[base + lofs[dl] + rank] = (int)(p & 0x1FFFFu);
    }
}

// Shared MFMA body: A-fragments provided; B from Wt; store bf16 Hs.
__device__ __forceinline__ void mfma_tail(short8 a0, short8 a1,
                                          const unsigned short* __restrict__ Wt,
                                          unsigned short* __restrict__ Hs,
                                          int row0, int r, int q, int N) {
    short8 bfrag[4][2];
#pragma unroll
    for (int ct = 0; ct < 4; ++ct)
#pragma unroll
        for (int kb = 0; kb < 2; ++kb)
            bfrag[ct][kb] = *(const short8*)(Wt + (ct * 16 + r) * 64 + q * 8 + 32 * kb);
    f32x4 acc[4];
#pragma unroll
    for (int ct = 0; ct < 4; ++ct) {
        acc[ct] = (f32x4){0.0f, 0.0f, 0.0f, 0.0f};
        acc[ct] = __builtin_amdgcn_mfma_f32_16x16x32_bf16(a0, bfrag[ct][0], acc[ct], 0, 0, 0);
        acc[ct] = __builtin_amdgcn_mfma_f32_16x16x32_bf16(a1, bfrag[ct][1], acc[ct], 0, 0, 0);
    }
#pragma unroll
    for (int reg = 0; reg < 4; ++reg) {
        int row = row0 + q * 4 + reg;
        if (row < N) {
            size_t base = (size_t)row * 64 + r;
#pragma unroll
            for (int ct = 0; ct < 4; ++ct)
                Hs[base + ct * 16] = f2bf(acc[ct][reg]);
        }
    }
}

// GEMM1: fp32 X in, dinv folded into A-fragment conversion.
__global__ __launch_bounds__(256) void k_gemm1(Ctx c0, Ctx c1, int nb0,
                                               const unsigned short* __restrict__ Wt,
                                               int nTiles, int N) {
    int b = blockIdx.x; Ctx c = c0;
    if (b >= nb0) { c = c1; b -= nb0; }
    int wave = threadIdx.x >> 6, lane = threadIdx.x & 63;
    int tile = b * 4 + wave;
    if (tile >= nTiles) return;
    int r = lane & 15, q = lane >> 4;
    int row0 = tile * 16;
    int row = row0 + r;
    int rr = row < N ? row : N - 1;
    float d = c.dinv[rr];
    const float* xrow = c.X + (size_t)rr * 64 + q * 8;
    short8 a0, a1;
#pragma unroll
    for (int j = 0; j < 8; ++j) a0[j] = (short)f2bf(xrow[j] * d);
#pragma unroll
    for (int j = 0; j < 8; ++j) a1[j] = (short)f2bf(xrow[32 + j] * d);
    mfma_tail(a0, a1, Wt, c.Hs, row0, r, q, N);
}

// GEMM2: bf16 Ab in (already dinv-scaled by aggregate1).
__global__ __launch_bounds__(256) void k_gemm2(Ctx c0, Ctx c1, int nb0,
                                               const unsigned short* __restrict__ Wt,
                                               int nTiles, int N) {
    int b = blockIdx.x; Ctx c = c0;
    if (b >= nb0) { c = c1; b -= nb0; }
    int wave = threadIdx.x >> 6, lane = threadIdx.x & 63;
    int tile = b * 4 + wave;
    if (tile >= nTiles) return;
    int r = lane & 15, q = lane >> 4;
    int row0 = tile * 16;
    const unsigned short* xrow = c.Ab + (size_t)(row0 + r) * 64 + q * 8;
    short8 a0 = *(const short8*)(xrow);
    short8 a1 = *(const short8*)(xrow + 32);
    mfma_tail(a0, a1, Wt, c.Hs, row0, r, q, N);
}

// 4 groups x 16 lanes, uint2 (8B) per lane: one VMEM inst per 4 edges.
// Lane s (0..15) covers channels 4s..4s+3; acc[0]={4s,4s+1}, acc[1]={4s+2,4s+3}.
// 2-level butterfly (xor 16, 32). All shfls exec-uniform.
__device__ __forceinline__ void agg_node(const unsigned short* __restrict__ Hs,
                                         const int* __restrict__ csr,
                                         int beg, int end, int lane, float2v* acc) {
    int g = lane >> 4, s = lane & 15;
    for (int base = beg; base < end; base += 64) {
        int m = end - base; if (m > 64) m = 64;
        int idx = (lane < m) ? csr[base + lane] : 0;   // coalesced
        int t = 0;
        for (; t + 8 <= m; t += 8) {                   // 2 gathers in flight
            int s0 = __shfl(idx, t + g, 64);
            int s1 = __shfl(idx, t + 4 + g, 64);
            uint2 h0 = *(const uint2*)(Hs + (size_t)s0 * 64 + s * 4);
            uint2 h1 = *(const uint2*)(Hs + (size_t)s1 * 64 + s * 4);
            acc[0] += up2(h0.x); acc[1] += up2(h0.y);
            acc[0] += up2(h1.x); acc[1] += up2(h1.y);
        }
        for (; t + 4 <= m; t += 4) {
            int s0 = __shfl(idx, t + g, 64);
            uint2 h0 = *(const uint2*)(Hs + (size_t)s0 * 64 + s * 4);
            acc[0] += up2(h0.x); acc[1] += up2(h0.y);
        }
        int rem = m - t;                               // 0..3
        if (rem > 0) {                                 // wave-uniform guard
            int sl = t + ((g < rem) ? g : 0);          // shfl exec-uniform
            int s0 = __shfl(idx, sl, 64);
            if (g < rem) {                             // divergent CONSUMER only
                uint2 h0 = *(const uint2*)(Hs + (size_t)s0 * 64 + s * 4);
                acc[0] += up2(h0.x); acc[1] += up2(h0.y);
            }
        }
    }
    // cross-group butterfly (bits 4,5): exec-uniform
#pragma unroll
    for (int k = 0; k < 2; ++k) {
        float2v o;
        o.x = __shfl_xor(acc[k].x, 16, 64); o.y = __shfl_xor(acc[k].y, 16, 64); acc[k] += o;
        o.x = __shfl_xor(acc[k].x, 32, 64); o.y = __shfl_xor(acc[k].y, 32, 64); acc[k] += o;
    }
}

// layer-1: Ab[d, f] = bf16( dinv[d] * relu(b[f] + dinv[d] * agg) )
__global__ __launch_bounds__(256) void k_agg1(Ctx c0, Ctx c1, int nb0,
                                              const float* __restrict__ bias, int n) {
    int b = blockIdx.x; Ctx c = c0;
    if (b >= nb0) { c = c1; b -= nb0; }
    int wave = threadIdx.x >> 6, lane = threadIdx.x & 63;
    int node = b * 4 + wave;
    if (node >= n) return;
    int beg = __builtin_amdgcn_readfirstlane(c.row_ptr[node]);
    int end = __builtin_amdgcn_readfirstlane(c.row_ptr[node + 1]);
    float2v acc[2] = {{0.f, 0.f}, {0.f, 0.f}};
    agg_node(c.Hs, c.csr, beg, end, lane, acc);
    if ((lane >> 4) == 0) {          // lanes 0..15 hold results (4 chans each)
        int s = lane;
        uint2 hsv = *(const uint2*)(c.Hs + (size_t)node * 64 + s * 4);
        float2v h0 = up2(hsv.x), h1 = up2(hsv.y);
        float4 bb = *(const float4*)(bias + s * 4);
        float d = c.dinv[node];
        float v0 = fmaxf(bb.x + d * (acc[0].x + h0.x), 0.0f) * d;
        float v1 = fmaxf(bb.y + d * (acc[0].y + h0.y), 0.0f) * d;
        float v2 = fmaxf(bb.z + d * (acc[1].x + h1.x), 0.0f) * d;
        float v3 = fmaxf(bb.w + d * (acc[1].y + h1.y), 0.0f) * d;
        ushort4 o;
        o.x = f2bf(v0); o.y = f2bf(v1); o.z = f2bf(v2); o.w = f2bf(v3);
        *(ushort4*)(c.Ab + (size_t)node * 64 + s * 4) = o;
    }
}

// layer-2: block-reduce 4 relu'd rows -> P[block, f]  (A never materialized)
__global__ __launch_bounds__(256) void k_agg2(Ctx c0, Ctx c1, int nb0,
                                              const float* __restrict__ bias, int n) {
    __shared__ float red[256];
    int b = blockIdx.x; Ctx c = c0;
    if (b >= nb0) { c = c1; b -= nb0; }
    int wave = threadIdx.x >> 6, lane = threadIdx.x & 63;
    int node = b * 4 + wave;
    bool active = node < n;
    int nn = active ? node : (n - 1);
    int beg = __builtin_amdgcn_readfirstlane(c.row_ptr[nn]);
    int end = __builtin_amdgcn_readfirstlane(c.row_ptr[nn + 1]);
    if (!active) { beg = 0; end = 0; }
    float2v acc[2] = {{0.f, 0.f}, {0.f, 0.f}};
    agg_node(c.Hs, c.csr, beg, end, lane, acc);
    if ((lane >> 4) == 0) {
        int s = lane;
        float4 v = {0.f, 0.f, 0.f, 0.f};
        if (active) {
            uint2 hsv = *(const uint2*)(c.Hs + (size_t)node * 64 + s * 4);
            float2v h0 = up2(hsv.x), h1 = up2(hsv.y);
            float4 bb = *(const float4*)(bias + s * 4);
            float d = c.dinv[node];
            v.x = fmaxf(bb.x + d * (acc[0].x + h0.x), 0.0f);
            v.y = fmaxf(bb.y + d * (acc[0].y + h0.y), 0.0f);
            v.z = fmaxf(bb.z + d * (acc[1].x + h1.x), 0.0f);
            v.w = fmaxf(bb.w + d * (acc[1].y + h1.y), 0.0f);
        }
        *(float4*)(&red[wave * 64 + s * 4]) = v;
    }
    __syncthreads();
    if (threadIdx.x < 64)
        c.P[(size_t)b * 64 + threadIdx.x] =
            red[threadIdx.x] + red[64 + threadIdx.x] +
            red[128 + threadIdx.x] + red[192 + threadIdx.x];
}

// colsum -> per-block partials in P2 (no atomics, no zero pass)
__global__ void k_colsum(Ctx c0, Ctx c1, int nb0, int rows) {
    int b = blockIdx.x; Ctx c = c0;
    if (b >= nb0) { c = c1; b -= nb0; }
    int f = threadIdx.x;  // 64
    float acc = 0.0f;
    for (int r = b; r < rows; r += nb0) acc += c.P[(size_t)r * 64 + f];
    c.P2[b * 64 + f] = acc;
}

// single-wave FC: reduce 256 partial rows, then out = fcb + (S/n) @ fcw^T
__global__ void k_fc(Ctx c0, Ctx c1, const float* __restrict__ fcw,
                     const float* __restrict__ fcb, int n) {
    Ctx c = blockIdx.x ? c1 : c0;
    __shared__ float S[64];
    int j = threadIdx.x;  // 64
    float s = 0.0f;
    for (int r = 0; r < 256; ++r) s += c.P2[r * 64 + j];
    S[j] = s;
    __syncthreads();
    float inv = 1.0f / (float)n;
    float acc = fcb[j];
#pragma unroll
    for (int k = 0; k < 64; ++k) acc += (S[k] * inv) * fcw[j * 64 + k];
    c.outp[j] = acc;
}

extern "C" void kernel_launch(void* const* d_in, const int* in_sizes, int n_in,
                              void* d_out, int out_size, void* d_ws, size_t ws_size,
                              hipStream_t stream) {
    const float* x[2]  = {(const float*)d_in[0], (const float*)d_in[1]};
    const int*   ei[2] = {(const int*)d_in[2], (const int*)d_in[3]};
    const float* W1  = (const float*)d_in[4];
    const float* b1  = (const float*)d_in[5];
    const float* W2  = (const float*)d_in[6];
    const float* b2  = (const float*)d_in[7];
    const float* fcw = (const float*)d_in[8];
    const float* fcb = (const float*)d_in[9];
    float* out = (float*)d_out;

    const int N  = in_sizes[0] / 64;
    const int E  = in_sizes[2] / 2;
    const int NF = N * 64;
    const int K  = (N + CHUNK - 1) / CHUNK;     // 782 buckets
    const int gGm = (N + 3) / 4;                // aggregate blocks
    const int nTiles = (N + 15) / 16;
    const int gMf = (nTiles + 3) / 4;
    const int gBin = (E + EPB - 1) / EPB;
    const int gK  = (K + TPB - 1) / TPB;

    auto al = [](size_t x) { return (x + 127) & ~(size_t)127; };
    size_t tempB = (size_t)K * CAP * 4;
    size_t abB   = ((size_t)NF + 64) * 2;
    size_t szRegion = al(tempB > abB ? tempB : abB);   // Ab aliases temp
    size_t szHs  = al((size_t)NF * 2);
    size_t szCsr = al((size_t)E * 4);
    size_t szRp  = al((size_t)(N + 1) * 4);
    size_t szDi  = al((size_t)N * 4);
    size_t szCu  = al((size_t)K * 4);
    size_t szBB  = al((size_t)K * 4);
    size_t szP   = al((size_t)gGm * 64 * 4);
    size_t szP2  = al((size_t)256 * 64 * 4);
    size_t setB  = szRegion + szHs + szCsr + szRp + szDi + szCu + szBB + szP + szP2;
    size_t wtB   = 2 * al(64 * 64 * 2);
    bool batched = ws_size >= wtB + 2 * setB;

    char* base = (char*)d_ws;
    unsigned short* Wt1 = (unsigned short*)base;
    unsigned short* Wt2 = (unsigned short*)(base + al(64 * 64 * 2));

    auto mkctx = [&](int g, char* p) {
        Ctx c;
        c.X = x[g]; c.esrc = ei[g]; c.edst = ei[g] + E;
        c.temp = (unsigned int*)p; c.Ab = (unsigned short*)p; p += szRegion;
        c.Hs = (unsigned short*)p; p += szHs;
        c.csr = (int*)p; p += szCsr;
        c.row_ptr = (int*)p; p += szRp;
        c.dinv = (float*)p; p += szDi;
        c.cursorG = (int*)p; p += szCu;
        c.bucketBase = (int*)p; p += szBB;
        c.P = (float*)p; p += szP;
        c.P2 = (float*)p;
        c.outp = out + g * 64;
        return c;
    };
    char* set0 = base + wtB;
    Ctx c0 = mkctx(0, set0);
    Ctx c1 = mkctx(1, batched ? set0 + setB : set0);   // fallback: shares set0

    k_prepW2<<<2, 256, 0, stream>>>(W1, W2, Wt1, Wt2);

    auto pipe = [&](Ctx A, Ctx B, int mult) {
        k_zeroCur<<<mult * gK, TPB, 0, stream>>>(A, B, gK, K);
        k_binA<<<mult * gBin, 256, 0, stream>>>(A, B, gBin, E, K);
        k_scanK<<<mult, 1024, 0, stream>>>(A, B, K, N, E);
        k_csrb<<<mult * K, 256, 0, stream>>>(A, B, K, N);
        k_gemm1<<<mult * gMf, 256, 0, stream>>>(A, B, gMf, Wt1, nTiles, N);
        k_agg1<<<mult * gGm, 256, 0, stream>>>(A, B, gGm, b1, N);
        k_gemm2<<<mult * gMf, 256, 0, stream>>>(A, B, gMf, Wt2, nTiles, N);
        k_agg2<<<mult * gGm, 256, 0, stream>>>(A, B, gGm, b2, N);
        k_colsum<<<mult * 256, 64, 0, stream>>>(A, B, 256, gGm);
        k_fc<<<mult, 64, 0, stream>>>(A, B, fcw, fcb, N);
    };

    if (batched) {
        pipe(c0, c1, 2);
    } else {
        pipe(c0, c0, 1);   // sequential, shared buffer set
        pipe(c1, c1, 1);
    }
}

// Round 13
// 413.177 us; speedup vs baseline: 1.0571x; 1.0571x over previous
//
#include <hip/hip_runtime.h>

// SiameseGNN round 13: fp8 (e4m3) feature rows -- one cache line per gather.
//
// R10/R11/R12 evidence: three different instruction schemes all pin the
// aggregate at ~86us (both graphs) = ~4.8 TB/s logical gather throughput,
// VALUBusy 55-71%, FETCH 171MB (42% L2 miss; Hs 12.8MB/graph vs 4MiB/XCD
// L2). Memory-path bound on the random 128B-row gather stream. Lever:
// halve the row. Hs stored fp8 e4m3 (HW v_cvt_pk_fp8_f32 / cvt_pk_f32_fp8):
// row = 64B = 1 line. Ab (MFMA input) stays bf16. Precision budget: e4m3
// ~3.6% rel std on 0.24-scale values, sqrt-cancellation through agg (x17)
// and mean-pool (~x77 effective) -> ~1-2e-4 added; expect absmax ~1e-3 vs
// threshold 2.7e-3. Geometry stays 4x16 (dword gather, 2-level butterfly).

#define TPB    256
#define CHUNK  128
#define SHIFT  7
#define KMAX   1024
#define CAP    2560
#define EPB    4096

typedef __attribute__((ext_vector_type(8))) short short8;
typedef __attribute__((ext_vector_type(4))) float f32x4;
typedef __attribute__((ext_vector_type(2))) float float2v;

struct Ctx {
    const float* X; const int* esrc; const int* edst;
    unsigned int* temp; unsigned short* Ab; unsigned char* Hs;
    int* csr; int* row_ptr; float* dinv; int* cursorG; int* bucketBase;
    float* P; float* P2; float* outp;
};

__device__ __forceinline__ unsigned short f2bf(float x) {
    union { float f; unsigned int i; } c; c.f = x;
    unsigned int r = c.i + 0x7FFFu + ((c.i >> 16) & 1u);   // RNE
    return (unsigned short)(r >> 16);
}
// fp8 e4m3 encode (RNE, HW op); byte in [7:0]
__device__ __forceinline__ unsigned char f2fp8(float x) {
    int p = __builtin_amdgcn_cvt_pk_fp8_f32(x, x, 0, false);
    return (unsigned char)(p & 0xFF);
}
// fp8 pair -> float2 (bytes [1:0] if hi=false, [3:2] if hi=true)
__device__ __forceinline__ float2v up8lo(unsigned int w) {
    return __builtin_amdgcn_cvt_pk_f32_fp8(w, false);
}
__device__ __forceinline__ float2v up8hi(unsigned int w) {
    return __builtin_amdgcn_cvt_pk_f32_fp8(w, true);
}

__global__ void k_prepW2(const float* __restrict__ W1, const float* __restrict__ W2,
                         unsigned short* __restrict__ Wt1, unsigned short* __restrict__ Wt2) {
    const float* W = blockIdx.x ? W2 : W1;
    unsigned short* Wt = blockIdx.x ? Wt2 : Wt1;
    for (int i = threadIdx.x; i < 64 * 64; i += 256) {
        int n = i >> 6, k = i & 63;
        Wt[i] = f2bf(W[k * 64 + n]);
    }
}

__global__ void k_zeroCur(Ctx c0, Ctx c1, int nb0, int K) {
    int b = blockIdx.x; Ctx c = c0;
    if (b >= nb0) { c = c1; b -= nb0; }
    int i = b * blockDim.x + threadIdx.x;
    if (i < K) c.cursorG[i] = 0;
}

// Bucket edges by dst (packed (dstLocal<<17)|src) -- contiguous segment writes.
__global__ __launch_bounds__(256) void k_binA(Ctx c0, Ctx c1, int nb0, int E, int K) {
    __shared__ int cnt[KMAX];
    __shared__ int segBase[KMAX];
    int b = blockIdx.x; Ctx c = c0;
    if (b >= nb0) { c = c1; b -= nb0; }
    int tid = threadIdx.x;
    for (int j = tid; j < K; j += 256) cnt[j] = 0;
    __syncthreads();
    int base = b * EPB;
#pragma unroll
    for (int k = 0; k < EPB / 256; ++k) {
        int e = base + k * 256 + tid;
        if (e < E) atomicAdd(&cnt[c.edst[e] >> SHIFT], 1);
    }
    __syncthreads();
    for (int j = tid; j < K; j += 256) {
        int cc = cnt[j];
        segBase[j] = cc ? atomicAdd(&c.cursorG[j], cc) : 0;
        cnt[j] = 0;
    }
    __syncthreads();
#pragma unroll
    for (int k = 0; k < EPB / 256; ++k) {
        int e = base + k * 256 + tid;
        if (e < E) {
            int d = c.edst[e];
            int bk = d >> SHIFT;
            int pos = segBase[bk] + atomicAdd(&cnt[bk], 1);
            if (pos < CAP)
                c.temp[(size_t)bk * CAP + pos] =
                    ((unsigned int)(d & (CHUNK - 1)) << 17) | (unsigned int)c.esrc[e];
        }
    }
}

__global__ __launch_bounds__(1024) void k_scanK(Ctx c0, Ctx c1, int K, int N, int E) {
    Ctx c = blockIdx.x ? c1 : c0;
    __shared__ int s[1024];
    int tid = threadIdx.x;
    int v = (tid < K) ? c.cursorG[tid] : 0;
    s[tid] = v;
    __syncthreads();
#pragma unroll
    for (int off = 1; off < 1024; off <<= 1) {
        int t = (tid >= off) ? s[tid - off] : 0;
        __syncthreads();
        s[tid] += t;
        __syncthreads();
    }
    if (tid < K) c.bucketBase[tid] = s[tid] - v;
    if (tid == 0) c.row_ptr[N] = E;
}

// Per-bucket LDS counting sort -> contiguous csr slice + row_ptr + dinv.
__global__ __launch_bounds__(256) void k_csrb(Ctx c0, Ctx c1, int nb0, int N) {
    __shared__ int deg[CHUNK];
    __shared__ int lofs[CHUNK];
    __shared__ int cur[CHUNK];
    int b = blockIdx.x; Ctx c = c0;
    if (b >= nb0) { c = c1; b -= nb0; }
    int tid = threadIdx.x;
    if (tid < CHUNK) deg[tid] = 0;
    __syncthreads();
    int cnt = c.cursorG[b]; if (cnt > CAP) cnt = CAP;
    const size_t tb = (size_t)b * CAP;
    for (int i = tid; i < cnt; i += 256) atomicAdd(&deg[c.temp[tb + i] >> 17], 1);
    __syncthreads();
    if (tid < CHUNK) lofs[tid] = deg[tid];
    __syncthreads();
#pragma unroll
    for (int off = 1; off < CHUNK; off <<= 1) {
        int t = (tid < CHUNK && tid >= off) ? lofs[tid - off] : 0;
        __syncthreads();
        if (tid < CHUNK) lofs[tid] += t;
        __syncthreads();
    }
    int base = c.bucketBase[b];
    if (tid < CHUNK) {
        int excl = lofs[tid] - deg[tid];
        lofs[tid] = excl;
        cur[tid] = 0;
        int node = b * CHUNK + tid;
        if (node < N) {
            c.row_ptr[node] = base + excl;
            c.dinv[node] = rsqrtf((float)deg[tid] + 1.0f);
        }
    }
    __syncthreads();
    for (int i = tid; i < cnt; i += 256) {
        unsigned int p = c.temp[tb + i];
        int dl = p >> 17;
        int rank = atomicAdd(&cur[dl], 1);
        c.csr[base + lofs[dl] + rank] = (int)(p & 0x1FFFFu);
    }
}

// Shared MFMA body: A-fragments provided; B from Wt; store fp8 Hs.
__device__ __forceinline__ void mfma_tail(short8 a0, short8 a1,
                                          const unsigned short* __restrict__ Wt,
                                          unsigned char* __restrict__ Hs,
                                          int row0, int r, int q, int N) {
    short8 bfrag[4][2];
#pragma unroll
    for (int ct = 0; ct < 4; ++ct)
#pragma unroll
        for (int kb = 0; kb < 2; ++kb)
            bfrag[ct][kb] = *(const short8*)(Wt + (ct * 16 + r) * 64 + q * 8 + 32 * kb);
    f32x4 acc[4];
#pragma unroll
    for (int ct = 0; ct < 4; ++ct) {
        acc[ct] = (f32x4){0.0f, 0.0f, 0.0f, 0.0f};
        acc[ct] = __builtin_amdgcn_mfma_f32_16x16x32_bf16(a0, bfrag[ct][0], acc[ct], 0, 0, 0);
        acc[ct] = __builtin_amdgcn_mfma_f32_16x16x32_bf16(a1, bfrag[ct][1], acc[ct], 0, 0, 0);
    }
#pragma unroll
    for (int reg = 0; reg < 4; ++reg) {
        int row = row0 + q * 4 + reg;
        if (row < N) {
            size_t base = (size_t)row * 64 + r;
#pragma unroll
            for (int ct = 0; ct < 4; ++ct)
                Hs[base + ct * 16] = f2fp8(acc[ct][reg]);
        }
    }
}

// GEMM1: fp32 X in, dinv folded into A-fragment conversion.
__global__ __launch_bounds__(256) void k_gemm1(Ctx c0, Ctx c1, int nb0,
                                               const unsigned short* __restrict__ Wt,
                                               int nTiles, int N) {
    int b = blockIdx.x; Ctx c = c0;
    if (b >= nb0) { c = c1; b -= nb0; }
    int wave = threadIdx.x >> 6, lane = threadIdx.x & 63;
    int tile = b * 4 + wave;
    if (tile >= nTiles) return;
    int r = lane & 15, q = lane >> 4;
    int row0 = tile * 16;
    int row = row0 + r;
    int rr = row < N ? row : N - 1;
    float d = c.dinv[rr];
    const float* xrow = c.X + (size_t)rr * 64 + q * 8;
    short8 a0, a1;
#pragma unroll
    for (int j = 0; j < 8; ++j) a0[j] = (short)f2bf(xrow[j] * d);
#pragma unroll
    for (int j = 0; j < 8; ++j) a1[j] = (short)f2bf(xrow[32 + j] * d);
    mfma_tail(a0, a1, Wt, c.Hs, row0, r, q, N);
}

// GEMM2: bf16 Ab in (already dinv-scaled by aggregate1).
__global__ __launch_bounds__(256) void k_gemm2(Ctx c0, Ctx c1, int nb0,
                                               const unsigned short* __restrict__ Wt,
                                               int nTiles, int N) {
    int b = blockIdx.x; Ctx c = c0;
    if (b >= nb0) { c = c1; b -= nb0; }
    int wave = threadIdx.x >> 6, lane = threadIdx.x & 63;
    int tile = b * 4 + wave;
    if (tile >= nTiles) return;
    int r = lane & 15, q = lane >> 4;
    int row0 = tile * 16;
    const unsigned short* xrow = c.Ab + (size_t)(row0 + r) * 64 + q * 8;
    short8 a0 = *(const short8*)(xrow);
    short8 a1 = *(const short8*)(xrow + 32);
    mfma_tail(a0, a1, Wt, c.Hs, row0, r, q, N);
}

// 4 groups x 16 lanes, one dword (4 fp8 chans) per lane: 64B row = 1 line.
// Lane s covers channels 4s..4s+3; acc[0]={4s,4s+1}, acc[1]={4s+2,4s+3}.
// 2-level butterfly (xor 16, 32). All shfls exec-uniform.
__device__ __forceinline__ void agg_node(const unsigned char* __restrict__ Hs,
                                         const int* __restrict__ csr,
                                         int beg, int end, int lane, float2v* acc) {
    int g = lane >> 4, s = lane & 15;
    for (int base = beg; base < end; base += 64) {
        int m = end - base; if (m > 64) m = 64;
        int idx = (lane < m) ? csr[base + lane] : 0;   // coalesced
        int t = 0;
        for (; t + 8 <= m; t += 8) {                   // 2 gathers in flight
            int s0 = __shfl(idx, t + g, 64);
            int s1 = __shfl(idx, t + 4 + g, 64);
            unsigned int h0 = *(const unsigned int*)(Hs + (size_t)s0 * 64 + s * 4);
            unsigned int h1 = *(const unsigned int*)(Hs + (size_t)s1 * 64 + s * 4);
            acc[0] += up8lo(h0); acc[1] += up8hi(h0);
            acc[0] += up8lo(h1); acc[1] += up8hi(h1);
        }
        for (; t + 4 <= m; t += 4) {
            int s0 = __shfl(idx, t + g, 64);
            unsigned int h0 = *(const unsigned int*)(Hs + (size_t)s0 * 64 + s * 4);
            acc[0] += up8lo(h0); acc[1] += up8hi(h0);
        }
        int rem = m - t;                               // 0..3
        if (rem > 0) {                                 // wave-uniform guard
            int sl = t + ((g < rem) ? g : 0);          // shfl exec-uniform
            int s0 = __shfl(idx, sl, 64);
            if (g < rem) {                             // divergent CONSUMER only
                unsigned int h0 = *(const unsigned int*)(Hs + (size_t)s0 * 64 + s * 4);
                acc[0] += up8lo(h0); acc[1] += up8hi(h0);
            }
        }
    }
    // cross-group butterfly (bits 4,5): exec-uniform
#pragma unroll
    for (int k = 0; k < 2; ++k) {
        float2v o;
        o.x = __shfl_xor(acc[k].x, 16, 64); o.y = __shfl_xor(acc[k].y, 16, 64); acc[k] += o;
        o.x = __shfl_xor(acc[k].x, 32, 64); o.y = __shfl_xor(acc[k].y, 32, 64); acc[k] += o;
    }
}

// layer-1: Ab[d, f] = bf16( dinv[d] * relu(b[f] + dinv[d] * agg) )
__global__ __launch_bounds__(256) void k_agg1(Ctx c0, Ctx c1, int nb0,
                                              const float* __restrict__ bias, int n) {
    int b = blockIdx.x; Ctx c = c0;
    if (b >= nb0) { c = c1; b -= nb0; }
    int wave = threadIdx.x >> 6, lane = threadIdx.x & 63;
    int node = b * 4 + wave;
    if (node >= n) return;
    int beg = __builtin_amdgcn_readfirstlane(c.row_ptr[node]);
    int end = __builtin_amdgcn_readfirstlane(c.row_ptr[node + 1]);
    float2v acc[2] = {{0.f, 0.f}, {0.f, 0.f}};
    agg_node(c.Hs, c.csr, beg, end, lane, acc);
    if ((lane >> 4) == 0) {          // lanes 0..15 hold results (4 chans each)
        int s = lane;
        unsigned int hv = *(const unsigned int*)(c.Hs + (size_t)node * 64 + s * 4);
        float2v h0 = up8lo(hv), h1 = up8hi(hv);
        float4 bb = *(const float4*)(bias + s * 4);
        float d = c.dinv[node];
        float v0 = fmaxf(bb.x + d * (acc[0].x + h0.x), 0.0f) * d;
        float v1 = fmaxf(bb.y + d * (acc[0].y + h0.y), 0.0f) * d;
        float v2 = fmaxf(bb.z + d * (acc[1].x + h1.x), 0.0f) * d;
        float v3 = fmaxf(bb.w + d * (acc[1].y + h1.y), 0.0f) * d;
        ushort4 o;
        o.x = f2bf(v0); o.y = f2bf(v1); o.z = f2bf(v2); o.w = f2bf(v3);
        *(ushort4*)(c.Ab + (size_t)node * 64 + s * 4) = o;
    }
}

// layer-2: block-reduce 4 relu'd rows -> P[block, f]  (A never materialized)
__global__ __launch_bounds__(256) void k_agg2(Ctx c0, Ctx c1, int nb0,
                                              const float* __restrict__ bias, int n) {
    __shared__ float red[256];
    int b = blockIdx.x; Ctx c = c0;
    if (b >= nb0) { c = c1; b -= nb0; }
    int wave = threadIdx.x >> 6, lane = threadIdx.x & 63;
    int node = b * 4 + wave;
    bool active = node < n;
    int nn = active ? node : (n - 1);
    int beg = __builtin_amdgcn_readfirstlane(c.row_ptr[nn]);
    int end = __builtin_amdgcn_readfirstlane(c.row_ptr[nn + 1]);
    if (!active) { beg = 0; end = 0; }
    float2v acc[2] = {{0.f, 0.f}, {0.f, 0.f}};
    agg_node(c.Hs, c.csr, beg, end, lane, acc);
    if ((lane >> 4) == 0) {
        int s = lane;
        float4 v = {0.f, 0.f, 0.f, 0.f};
        if (active) {
            unsigned int hv = *(const unsigned int*)(c.Hs + (size_t)node * 64 + s * 4);
            float2v h0 = up8lo(hv), h1 = up8hi(hv);
            float4 bb = *(const float4*)(bias + s * 4);
            float d = c.dinv[node];
            v.x = fmaxf(bb.x + d * (acc[0].x + h0.x), 0.0f);
            v.y = fmaxf(bb.y + d * (acc[0].y + h0.y), 0.0f);
            v.z = fmaxf(bb.z + d * (acc[1].x + h1.x), 0.0f);
            v.w = fmaxf(bb.w + d * (acc[1].y + h1.y), 0.0f);
        }
        *(float4*)(&red[wave * 64 + s * 4]) = v;
    }
    __syncthreads();
    if (threadIdx.x < 64)
        c.P[(size_t)b * 64 + threadIdx.x] =
            red[threadIdx.x] + red[64 + threadIdx.x] +
            red[128 + threadIdx.x] + red[192 + threadIdx.x];
}

// colsum -> per-block partials in P2 (no atomics, no zero pass)
__global__ void k_colsum(Ctx c0, Ctx c1, int nb0, int rows) {
    int b = blockIdx.x; Ctx c = c0;
    if (b >= nb0) { c = c1; b -= nb0; }
    int f = threadIdx.x;  // 64
    float acc = 0.0f;
    for (int r = b; r < rows; r += nb0) acc += c.P[(size_t)r * 64 + f];
    c.P2[b * 64 + f] = acc;
}

// single-wave FC: reduce 256 partial rows, then out = fcb + (S/n) @ fcw^T
__global__ void k_fc(Ctx c0, Ctx c1, const float* __restrict__ fcw,
                     const float* __restrict__ fcb, int n) {
    Ctx c = blockIdx.x ? c1 : c0;
    __shared__ float S[64];
    int j = threadIdx.x;  // 64
    float s = 0.0f;
    for (int r = 0; r < 256; ++r) s += c.P2[r * 64 + j];
    S[j] = s;
    __syncthreads();
    float inv = 1.0f / (float)n;
    float acc = fcb[j];
#pragma unroll
    for (int k = 0; k < 64; ++k) acc += (S[k] * inv) * fcw[j * 64 + k];
    c.outp[j] = acc;
}

extern "C" void kernel_launch(void* const* d_in, const int* in_sizes, int n_in,
                              void* d_out, int out_size, void* d_ws, size_t ws_size,
                              hipStream_t stream) {
    const float* x[2]  = {(const float*)d_in[0], (const float*)d_in[1]};
    const int*   ei[2] = {(const int*)d_in[2], (const int*)d_in[3]};
    const float* W1  = (const float*)d_in[4];
    const float* b1  = (const float*)d_in[5];
    const float* W2  = (const float*)d_in[6];
    const float* b2  = (const float*)d_in[7];
    const float* fcw = (const float*)d_in[8];
    const float* fcb = (const float*)d_in[9];
    float* out = (float*)d_out;

    const int N  = in_sizes[0] / 64;
    const int E  = in_sizes[2] / 2;
    const int NF = N * 64;
    const int K  = (N + CHUNK - 1) / CHUNK;     // 782 buckets
    const int gGm = (N + 3) / 4;                // aggregate blocks
    const int nTiles = (N + 15) / 16;
    const int gMf = (nTiles + 3) / 4;
    const int gBin = (E + EPB - 1) / EPB;
    const int gK  = (K + TPB - 1) / TPB;

    auto al = [](size_t x) { return (x + 127) & ~(size_t)127; };
    size_t tempB = (size_t)K * CAP * 4;
    size_t abB   = ((size_t)NF + 64) * 2;
    size_t szRegion = al(tempB > abB ? tempB : abB);   // Ab aliases temp
    size_t szHs  = al((size_t)NF + 64);                // fp8: 1 B/elem
    size_t szCsr = al((size_t)E * 4);
    size_t szRp  = al((size_t)(N + 1) * 4);
    size_t szDi  = al((size_t)N * 4);
    size_t szCu  = al((size_t)K * 4);
    size_t szBB  = al((size_t)K * 4);
    size_t szP   = al((size_t)gGm * 64 * 4);
    size_t szP2  = al((size_t)256 * 64 * 4);
    size_t setB  = szRegion + szHs + szCsr + szRp + szDi + szCu + szBB + szP + szP2;
    size_t wtB   = 2 * al(64 * 64 * 2);
    bool batched = ws_size >= wtB + 2 * setB;

    char* base = (char*)d_ws;
    unsigned short* Wt1 = (unsigned short*)base;
    unsigned short* Wt2 = (unsigned short*)(base + al(64 * 64 * 2));

    auto mkctx = [&](int g, char* p) {
        Ctx c;
        c.X = x[g]; c.esrc = ei[g]; c.edst = ei[g] + E;
        c.temp = (unsigned int*)p; c.Ab = (unsigned short*)p; p += szRegion;
        c.Hs = (unsigned char*)p; p += szHs;
        c.csr = (int*)p; p += szCsr;
        c.row_ptr = (int*)p; p += szRp;
        c.dinv = (float*)p; p += szDi;
        c.cursorG = (int*)p; p += szCu;
        c.bucketBase = (int*)p; p += szBB;
        c.P = (float*)p; p += szP;
        c.P2 = (float*)p;
        c.outp = out + g * 64;
        return c;
    };
    char* set0 = base + wtB;
    Ctx c0 = mkctx(0, set0);
    Ctx c1 = mkctx(1, batched ? set0 + setB : set0);   // fallback: shares set0

    k_prepW2<<<2, 256, 0, stream>>>(W1, W2, Wt1, Wt2);

    auto pipe = [&](Ctx A, Ctx B, int mult) {
        k_zeroCur<<<mult * gK, TPB, 0, stream>>>(A, B, gK, K);
        k_binA<<<mult * gBin, 256, 0, stream>>>(A, B, gBin, E, K);
        k_scanK<<<mult, 1024, 0, stream>>>(A, B, K, N, E);
        k_csrb<<<mult * K, 256, 0, stream>>>(A, B, K, N);
        k_gemm1<<<mult * gMf, 256, 0, stream>>>(A, B, gMf, Wt1, nTiles, N);
        k_agg1<<<mult * gGm, 256, 0, stream>>>(A, B, gGm, b1, N);
        k_gemm2<<<mult * gMf, 256, 0, stream>>>(A, B, gMf, Wt2, nTiles, N);
        k_agg2<<<mult * gGm, 256, 0, stream>>>(A, B, gGm, b2, N);
        k_colsum<<<mult * 256, 64, 0, stream>>>(A, B, 256, gGm);
        k_fc<<<mult, 64, 0, stream>>>(A, B, fcw, fcb, N);
    };

    if (batched) {
        pipe(c0, c1, 2);
    } else {
        pipe(c0, c0, 1);   // sequential, shared buffer set
        pipe(c1, c1, 1);
    }
}

// Round 14
// 399.223 us; speedup vs baseline: 1.0940x; 1.0350x over previous
//
#include <hip/hip_runtime.h>

// SiameseGNN round 14: padded reserve-cursors (atomic de-serialization) +
// 2-nodes-per-wave aggregate.
//
// R13 evidence:
//  - k_binA 82.6us, VALU 2%, HBM 17%: ~610K global atomics onto 49 cache
//    lines of cursorG -> 12.5K same-line atomics x ~15cyc = ~78us serial
//    chain == measured. Fix: 1 cursor per 64B line (stride 16) + EPB 8192
//    (halves atomics, doubles segment size -> less write-amp).
//  - aggregate pinned ~80us across 4 instruction schemes; VALUBusy 55%,
//    fixed per-node cost (butterfly 12 + epilogue 15 + setup) over deg~17.
//    Fix: half-wave per node (2 groups x 16 lanes): 2 nodes/wave, 1-level
//    butterfly (3 ops/node), shared epilogue, predicated remainder.

#define TPB    256
#define CHUNK  128
#define SHIFT  7
#define KMAX   1024
#define CAP    2560
#define EPB    8192
#define CPAD   16      // cursorG stride (ints): 1 cursor per 64B line

typedef __attribute__((ext_vector_type(8))) short short8;
typedef __attribute__((ext_vector_type(4))) float f32x4;
typedef __attribute__((ext_vector_type(2))) float float2v;

struct Ctx {
    const float* X; const int* esrc; const int* edst;
    unsigned int* temp; unsigned short* Ab; unsigned char* Hs;
    int* csr; int* row_ptr; float* dinv; int* cursorG; int* bucketBase;
    float* P; float* P2; float* outp;
};

__device__ __forceinline__ unsigned short f2bf(float x) {
    union { float f; unsigned int i; } c; c.f = x;
    unsigned int r = c.i + 0x7FFFu + ((c.i >> 16) & 1u);   // RNE
    return (unsigned short)(r >> 16);
}
// fp8 e4m3 encode (HW op); byte in [7:0]
__device__ __forceinline__ unsigned char f2fp8(float x) {
    int p = __builtin_amdgcn_cvt_pk_fp8_f32(x, x, 0, false);
    return (unsigned char)(p & 0xFF);
}
__device__ __forceinline__ float2v up8lo(unsigned int w) {
    return __builtin_amdgcn_cvt_pk_f32_fp8(w, false);
}
__device__ __forceinline__ float2v up8hi(unsigned int w) {
    return __builtin_amdgcn_cvt_pk_f32_fp8(w, true);
}

__global__ void k_prepW2(const float* __restrict__ W1, const float* __restrict__ W2,
                         unsigned short* __restrict__ Wt1, unsigned short* __restrict__ Wt2) {
    const float* W = blockIdx.x ? W2 : W1;
    unsigned short* Wt = blockIdx.x ? Wt2 : Wt1;
    for (int i = threadIdx.x; i < 64 * 64; i += 256) {
        int n = i >> 6, k = i & 63;
        Wt[i] = f2bf(W[k * 64 + n]);
    }
}

__global__ void k_zeroCur(Ctx c0, Ctx c1, int nb0, int K) {
    int b = blockIdx.x; Ctx c = c0;
    if (b >= nb0) { c = c1; b -= nb0; }
    int i = b * blockDim.x + threadIdx.x;
    if (i < K) c.cursorG[i * CPAD] = 0;
}

// Bucket edges by dst (packed (dstLocal<<17)|src) -- contiguous segment writes.
// Reserve atomics hit PADDED cursors (one line each): no same-line serialization.
__global__ __launch_bounds__(256) void k_binA(Ctx c0, Ctx c1, int nb0, int E, int K) {
    __shared__ int cnt[KMAX];
    __shared__ int segBase[KMAX];
    int b = blockIdx.x; Ctx c = c0;
    if (b >= nb0) { c = c1; b -= nb0; }
    int tid = threadIdx.x;
    for (int j = tid; j < K; j += 256) cnt[j] = 0;
    __syncthreads();
    int base = b * EPB;
#pragma unroll
    for (int k = 0; k < EPB / 256; ++k) {
        int e = base + k * 256 + tid;
        if (e < E) atomicAdd(&cnt[c.edst[e] >> SHIFT], 1);
    }
    __syncthreads();
    for (int j = tid; j < K; j += 256) {
        int cc = cnt[j];
        segBase[j] = cc ? atomicAdd(&c.cursorG[j * CPAD], cc) : 0;
        cnt[j] = 0;
    }
    __syncthreads();
#pragma unroll
    for (int k = 0; k < EPB / 256; ++k) {
        int e = base + k * 256 + tid;
        if (e < E) {
            int d = c.edst[e];
            int bk = d >> SHIFT;
            int pos = segBase[bk] + atomicAdd(&cnt[bk], 1);
            if (pos < CAP)
                c.temp[(size_t)bk * CAP + pos] =
                    ((unsigned int)(d & (CHUNK - 1)) << 17) | (unsigned int)c.esrc[e];
        }
    }
}

__global__ __launch_bounds__(1024) void k_scanK(Ctx c0, Ctx c1, int K, int N, int E) {
    Ctx c = blockIdx.x ? c1 : c0;
    __shared__ int s[1024];
    int tid = threadIdx.x;
    int v = (tid < K) ? c.cursorG[tid * CPAD] : 0;
    s[tid] = v;
    __syncthreads();
#pragma unroll
    for (int off = 1; off < 1024; off <<= 1) {
        int t = (tid >= off) ? s[tid - off] : 0;
        __syncthreads();
        s[tid] += t;
        __syncthreads();
    }
    if (tid < K) c.bucketBase[tid] = s[tid] - v;
    if (tid == 0) c.row_ptr[N] = E;
}

// Per-bucket LDS counting sort -> contiguous csr slice + row_ptr + dinv.
__global__ __launch_bounds__(256) void k_csrb(Ctx c0, Ctx c1, int nb0, int N) {
    __shared__ int deg[CHUNK];
    __shared__ int lofs[CHUNK];
    __shared__ int cur[CHUNK];
    int b = blockIdx.x; Ctx c = c0;
    if (b >= nb0) { c = c1; b -= nb0; }
    int tid = threadIdx.x;
    if (tid < CHUNK) deg[tid] = 0;
    __syncthreads();
    int cnt = c.cursorG[b * CPAD]; if (cnt > CAP) cnt = CAP;
    const size_t tb = (size_t)b * CAP;
    for (int i = tid; i < cnt; i += 256) atomicAdd(&deg[c.temp[tb + i] >> 17], 1);
    __syncthreads();
    if (tid < CHUNK) lofs[tid] = deg[tid];
    __syncthreads();
#pragma unroll
    for (int off = 1; off < CHUNK; off <<= 1) {
        int t = (tid < CHUNK && tid >= off) ? lofs[tid - off] : 0;
        __syncthreads();
        if (tid < CHUNK) lofs[tid] += t;
        __syncthreads();
    }
    int base = c.bucketBase[b];
    if (tid < CHUNK) {
        int excl = lofs[tid] - deg[tid];
        lofs[tid] = excl;
        cur[tid] = 0;
        int node = b * CHUNK + tid;
        if (node < N) {
            c.row_ptr[node] = base + excl;
            c.dinv[node] = rsqrtf((float)deg[tid] + 1.0f);
        }
    }
    __syncthreads();
    for (int i = tid; i < cnt; i += 256) {
        unsigned int p = c.temp[tb + i];
        int dl = p >> 17;
        int rank = atomicAdd(&cur[dl], 1);
        c.csr[base + lofs[dl] + rank] = (int)(p & 0x1FFFFu);
    }
}

// Shared MFMA body: A-fragments provided; B from Wt; store fp8 Hs.
__device__ __forceinline__ void mfma_tail(short8 a0, short8 a1,
                                          const unsigned short* __restrict__ Wt,
                                          unsigned char* __restrict__ Hs,
                                          int row0, int r, int q, int N) {
    short8 bfrag[4][2];
#pragma unroll
    for (int ct = 0; ct < 4; ++ct)
#pragma unroll
        for (int kb = 0; kb < 2; ++kb)
            bfrag[ct][kb] = *(const short8*)(Wt + (ct * 16 + r) * 64 + q * 8 + 32 * kb);
    f32x4 acc[4];
#pragma unroll
    for (int ct = 0; ct < 4; ++ct) {
        acc[ct] = (f32x4){0.0f, 0.0f, 0.0f, 0.0f};
        acc[ct] = __builtin_amdgcn_mfma_f32_16x16x32_bf16(a0, bfrag[ct][0], acc[ct], 0, 0, 0);
        acc[ct] = __builtin_amdgcn_mfma_f32_16x16x32_bf16(a1, bfrag[ct][1], acc[ct], 0, 0, 0);
    }
#pragma unroll
    for (int reg = 0; reg < 4; ++reg) {
        int row = row0 + q * 4 + reg;
        if (row < N) {
            size_t base = (size_t)row * 64 + r;
#pragma unroll
            for (int ct = 0; ct < 4; ++ct)
                Hs[base + ct * 16] = f2fp8(acc[ct][reg]);
        }
    }
}

// GEMM1: fp32 X in, dinv folded into A-fragment conversion.
__global__ __launch_bounds__(256) void k_gemm1(Ctx c0, Ctx c1, int nb0,
                                               const unsigned short* __restrict__ Wt,
                                               int nTiles, int N) {
    int b = blockIdx.x; Ctx c = c0;
    if (b >= nb0) { c = c1; b -= nb0; }
    int wave = threadIdx.x >> 6, lane = threadIdx.x & 63;
    int tile = b * 4 + wave;
    if (tile >= nTiles) return;
    int r = lane & 15, q = lane >> 4;
    int row0 = tile * 16;
    int row = row0 + r;
    int rr = row < N ? row : N - 1;
    float d = c.dinv[rr];
    const float* xrow = c.X + (size_t)rr * 64 + q * 8;
    short8 a0, a1;
#pragma unroll
    for (int j = 0; j < 8; ++j) a0[j] = (short)f2bf(xrow[j] * d);
#pragma unroll
    for (int j = 0; j < 8; ++j) a1[j] = (short)f2bf(xrow[32 + j] * d);
    mfma_tail(a0, a1, Wt, c.Hs, row0, r, q, N);
}

// GEMM2: bf16 Ab in (already dinv-scaled by aggregate1).
__global__ __launch_bounds__(256) void k_gemm2(Ctx c0, Ctx c1, int nb0,
                                               const unsigned short* __restrict__ Wt,
                                               int nTiles, int N) {
    int b = blockIdx.x; Ctx c = c0;
    if (b >= nb0) { c = c1; b -= nb0; }
    int wave = threadIdx.x >> 6, lane = threadIdx.x & 63;
    int tile = b * 4 + wave;
    if (tile >= nTiles) return;
    int r = lane & 15, q = lane >> 4;
    int row0 = tile * 16;
    const unsigned short* xrow = c.Ab + (size_t)(row0 + r) * 64 + q * 8;
    short8 a0 = *(const short8*)(xrow);
    short8 a1 = *(const short8*)(xrow + 32);
    mfma_tail(a0, a1, Wt, c.Hs, row0, r, q, N);
}

// 2 nodes per wave: half h (lane>>5) owns one node. Within a half: 2 groups
// x 16 lanes; lane s covers channels 4s..4s+3 (one fp8 dword = 64B row/grp).
// One coalesced 32-index load per half per 32-edge batch; per 4-edge step
// each group does 2 predicated gathers (slots t+g, t+2+g). All shfls
// exec-uniform. 1-level butterfly (xor 16) merges the half's 2 groups.
__device__ __forceinline__ void agg_node2(const unsigned char* __restrict__ Hs,
                                          const int* __restrict__ csr,
                                          int beg, int deg, int maxd, int lane,
                                          float2v* acc) {
    int hbase = lane & 32;          // half base lane (0 or 32)
    int hl = lane & 31;             // lane within half
    int g = (lane >> 4) & 1;        // group within half
    int s = lane & 15;
    for (int base = 0; base < maxd; base += 32) {
        int idx = (base + hl < deg) ? csr[beg + base + hl] : 0;   // coalesced/half
        int mW = maxd - base; if (mW > 32) mW = 32;               // wave-uniform
        for (int t = 0; t < mW; t += 4) {
            int s0 = __shfl(idx, hbase + t + g, 64);              // exec-uniform
            int s1 = __shfl(idx, hbase + t + 2 + g, 64);
            if (base + t + g < deg) {
                unsigned int h0 = *(const unsigned int*)(Hs + (size_t)s0 * 64 + s * 4);
                acc[0] += up8lo(h0); acc[1] += up8hi(h0);
            }
            if (base + t + 2 + g < deg) {
                unsigned int h1 = *(const unsigned int*)(Hs + (size_t)s1 * 64 + s * 4);
                acc[0] += up8lo(h1); acc[1] += up8hi(h1);
            }
        }
    }
    // merge groups within each half (bit 4); does not cross halves
#pragma unroll
    for (int k = 0; k < 2; ++k) {
        float2v o;
        o.x = __shfl_xor(acc[k].x, 16, 64); o.y = __shfl_xor(acc[k].y, 16, 64);
        acc[k] += o;
    }
}

// layer-1: Ab[d, f] = bf16( dinv[d] * relu(b[f] + dinv[d] * agg) )
// 8 nodes per block (4 waves x 2).
__global__ __launch_bounds__(256) void k_agg1(Ctx c0, Ctx c1, int nb0,
                                              const float* __restrict__ bias, int n) {
    int b = blockIdx.x; Ctx c = c0;
    if (b >= nb0) { c = c1; b -= nb0; }
    int wave = threadIdx.x >> 6, lane = threadIdx.x & 63;
    int h = lane >> 5;
    int node = b * 8 + wave * 2 + h;
    int nd = node < n ? node : 0;
    int beg = c.row_ptr[nd];
    int deg = (node < n) ? (c.row_ptr[nd + 1] - beg) : 0;
    int od = __shfl_xor(deg, 32, 64);
    int maxd = deg > od ? deg : od;      // wave-uniform
    float2v acc[2] = {{0.f, 0.f}, {0.f, 0.f}};
    agg_node2(c.Hs, c.csr, beg, deg, maxd, lane, acc);
    if (((lane >> 4) & 1) == 0 && node < n) {   // lanes 0-15 (A), 32-47 (B)
        int s = lane & 15;
        unsigned int hv = *(const unsigned int*)(c.Hs + (size_t)node * 64 + s * 4);
        float2v h0 = up8lo(hv), h1 = up8hi(hv);
        float4 bb = *(const float4*)(bias + s * 4);
        float d = c.dinv[node];
        float v0 = fmaxf(bb.x + d * (acc[0].x + h0.x), 0.0f) * d;
        float v1 = fmaxf(bb.y + d * (acc[0].y + h0.y), 0.0f) * d;
        float v2 = fmaxf(bb.z + d * (acc[1].x + h1.x), 0.0f) * d;
        float v3 = fmaxf(bb.w + d * (acc[1].y + h1.y), 0.0f) * d;
        ushort4 o;
        o.x = f2bf(v0); o.y = f2bf(v1); o.z = f2bf(v2); o.w = f2bf(v3);
        *(ushort4*)(c.Ab + (size_t)node * 64 + s * 4) = o;
    }
}

// layer-2: block-reduce 8 relu'd rows -> P[block, f]  (A never materialized)
__global__ __launch_bounds__(256) void k_agg2(Ctx c0, Ctx c1, int nb0,
                                              const float* __restrict__ bias, int n) {
    __shared__ float red[8 * 64];
    int b = blockIdx.x; Ctx c = c0;
    if (b >= nb0) { c = c1; b -= nb0; }
    int wave = threadIdx.x >> 6, lane = threadIdx.x & 63;
    int h = lane >> 5;
    int node = b * 8 + wave * 2 + h;
    int nd = node < n ? node : 0;
    int beg = c.row_ptr[nd];
    int deg = (node < n) ? (c.row_ptr[nd + 1] - beg) : 0;
    int od = __shfl_xor(deg, 32, 64);
    int maxd = deg > od ? deg : od;
    float2v acc[2] = {{0.f, 0.f}, {0.f, 0.f}};
    agg_node2(c.Hs, c.csr, beg, deg, maxd, lane, acc);
    if (((lane >> 4) & 1) == 0) {
        int s = lane & 15;
        float4 v = {0.f, 0.f, 0.f, 0.f};
        if (node < n) {
            unsigned int hv = *(const unsigned int*)(c.Hs + (size_t)node * 64 + s * 4);
            float2v h0 = up8lo(hv), h1 = up8hi(hv);
            float4 bb = *(const float4*)(bias + s * 4);
            float d = c.dinv[node];
            v.x = fmaxf(bb.x + d * (acc[0].x + h0.x), 0.0f);
            v.y = fmaxf(bb.y + d * (acc[0].y + h0.y), 0.0f);
            v.z = fmaxf(bb.z + d * (acc[1].x + h1.x), 0.0f);
            v.w = fmaxf(bb.w + d * (acc[1].y + h1.y), 0.0f);
        }
        *(float4*)(&red[(wave * 2 + h) * 64 + s * 4]) = v;
    }
    __syncthreads();
    if (threadIdx.x < 64) {
        float acc8 = 0.0f;
#pragma unroll
        for (int r = 0; r < 8; ++r) acc8 += red[r * 64 + threadIdx.x];
        c.P[(size_t)b * 64 + threadIdx.x] = acc8;
    }
}

// colsum -> per-block partials in P2 (no atomics, no zero pass)
__global__ void k_colsum(Ctx c0, Ctx c1, int nb0, int rows) {
    int b = blockIdx.x; Ctx c = c0;
    if (b >= nb0) { c = c1; b -= nb0; }
    int f = threadIdx.x;  // 64
    float acc = 0.0f;
    for (int r = b; r < rows; r += nb0) acc += c.P[(size_t)r * 64 + f];
    c.P2[b * 64 + f] = acc;
}

// single-wave FC: reduce 256 partial rows, then out = fcb + (S/n) @ fcw^T
__global__ void k_fc(Ctx c0, Ctx c1, const float* __restrict__ fcw,
                     const float* __restrict__ fcb, int n) {
    Ctx c = blockIdx.x ? c1 : c0;
    __shared__ float S[64];
    int j = threadIdx.x;  // 64
    float s = 0.0f;
    for (int r = 0; r < 256; ++r) s += c.P2[r * 64 + j];
    S[j] = s;
    __syncthreads();
    float inv = 1.0f / (float)n;
    float acc = fcb[j];
#pragma unroll
    for (int k = 0; k < 64; ++k) acc += (S[k] * inv) * fcw[j * 64 + k];
    c.outp[j] = acc;
}

extern "C" void kernel_launch(void* const* d_in, const int* in_sizes, int n_in,
                              void* d_out, int out_size, void* d_ws, size_t ws_size,
                              hipStream_t stream) {
    const float* x[2]  = {(const float*)d_in[0], (const float*)d_in[1]};
    const int*   ei[2] = {(const int*)d_in[2], (const int*)d_in[3]};
    const float* W1  = (const float*)d_in[4];
    const float* b1  = (const float*)d_in[5];
    const float* W2  = (const float*)d_in[6];
    const float* b2  = (const float*)d_in[7];
    const float* fcw = (const float*)d_in[8];
    const float* fcb = (const float*)d_in[9];
    float* out = (float*)d_out;

    const int N  = in_sizes[0] / 64;
    const int E  = in_sizes[2] / 2;
    const int NF = N * 64;
    const int K  = (N + CHUNK - 1) / CHUNK;     // 782 buckets
    const int gGm = (N + 7) / 8;                // aggregate blocks (8 nodes each)
    const int nTiles = (N + 15) / 16;
    const int gMf = (nTiles + 3) / 4;
    const int gBin = (E + EPB - 1) / EPB;
    const int gK  = (K + TPB - 1) / TPB;

    auto al = [](size_t x) { return (x + 127) & ~(size_t)127; };
    size_t tempB = (size_t)K * CAP * 4;
    size_t abB   = ((size_t)NF + 64) * 2;
    size_t szRegion = al(tempB > abB ? tempB : abB);   // Ab aliases temp
    size_t szHs  = al((size_t)NF + 64);                // fp8: 1 B/elem
    size_t szCsr = al((size_t)E * 4);
    size_t szRp  = al((size_t)(N + 1) * 4);
    size_t szDi  = al((size_t)N * 4);
    size_t szCu  = al((size_t)K * CPAD * 4);           // padded cursors
    size_t szBB  = al((size_t)K * 4);
    size_t szP   = al((size_t)gGm * 64 * 4);
    size_t szP2  = al((size_t)256 * 64 * 4);
    size_t setB  = szRegion + szHs + szCsr + szRp + szDi + szCu + szBB + szP + szP2;
    size_t wtB   = 2 * al(64 * 64 * 2);
    bool batched = ws_size >= wtB + 2 * setB;

    char* base = (char*)d_ws;
    unsigned short* Wt1 = (unsigned short*)base;
    unsigned short* Wt2 = (unsigned short*)(base + al(64 * 64 * 2));

    auto mkctx = [&](int g, char* p) {
        Ctx c;
        c.X = x[g]; c.esrc = ei[g]; c.edst = ei[g] + E;
        c.temp = (unsigned int*)p; c.Ab = (unsigned short*)p; p += szRegion;
        c.Hs = (unsigned char*)p; p += szHs;
        c.csr = (int*)p; p += szCsr;
        c.row_ptr = (int*)p; p += szRp;
        c.dinv = (float*)p; p += szDi;
        c.cursorG = (int*)p; p += szCu;
        c.bucketBase = (int*)p; p += szBB;
        c.P = (float*)p; p += szP;
        c.P2 = (float*)p;
        c.outp = out + g * 64;
        return c;
    };
    char* set0 = base + wtB;
    Ctx c0 = mkctx(0, set0);
    Ctx c1 = mkctx(1, batched ? set0 + setB : set0);   // fallback: shares set0

    k_prepW2<<<2, 256, 0, stream>>>(W1, W2, Wt1, Wt2);

    auto pipe = [&](Ctx A, Ctx B, int mult) {
        k_zeroCur<<<mult * gK, TPB, 0, stream>>>(A, B, gK, K);
        k_binA<<<mult * gBin, 256, 0, stream>>>(A, B, gBin, E, K);
        k_scanK<<<mult, 1024, 0, stream>>>(A, B, K, N, E);
        k_csrb<<<mult * K, 256, 0, stream>>>(A, B, K, N);
        k_gemm1<<<mult * gMf, 256, 0, stream>>>(A, B, gMf, Wt1, nTiles, N);
        k_agg1<<<mult * gGm, 256, 0, stream>>>(A, B, gGm, b1, N);
        k_gemm2<<<mult * gMf, 256, 0, stream>>>(A, B, gMf, Wt2, nTiles, N);
        k_agg2<<<mult * gGm, 256, 0, stream>>>(A, B, gGm, b2, N);
        k_colsum<<<mult * 256, 64, 0, stream>>>(A, B, 256, gGm);
        k_fc<<<mult, 64, 0, stream>>>(A, B, fcw, fcb, N);
    };

    if (batched) {
        pipe(c0, c1, 2);
    } else {
        pipe(c0, c0, 1);   // sequential, shared buffer set
        pipe(c1, c1, 1);
    }
}

// Round 15
// 392.840 us; speedup vs baseline: 1.1118x; 1.0163x over previous
//
#include <hip/hip_runtime.h>

// SiameseGNN round 15: binA v2 -- LDS counting sort + burst segment writes.
//
// R14 post-mortem: padded cursors did NOT move binA (83us, VALU 2%) -- the
// limiter is write-drain, not atomic serialization. WRITE 84MB vs 13MB
// payload: each block fills ~782 segments one random dword at a time over
// its whole lifetime; ~48K dirty lines/XCD churn the 64K-line L2 -> partial
// lines evicted+rewritten repeatedly (6.5x amp). Fix: sort the block's 8192
// edges by bucket in LDS (count -> scan -> scatter into sorted[]+bkt[]),
// then write each bucket run as one contiguous burst. Line set identical;
// each line now filled completely while hot -> written back once.
// Aggregates (2 nodes/wave, fp8 rows), csrb, gemms unchanged from R14.

#define TPB    256
#define CHUNK  128
#define SHIFT  7
#define KMAX   1024
#define CAP    2560
#define EPB    8192
#define CPAD   16      // cursorG stride (ints)

typedef __attribute__((ext_vector_type(8))) short short8;
typedef __attribute__((ext_vector_type(4))) float f32x4;
typedef __attribute__((ext_vector_type(2))) float float2v;

struct Ctx {
    const float* X; const int* esrc; const int* edst;
    unsigned int* temp; unsigned short* Ab; unsigned char* Hs;
    int* csr; int* row_ptr; float* dinv; int* cursorG; int* bucketBase;
    float* P; float* P2; float* outp;
};

__device__ __forceinline__ unsigned short f2bf(float x) {
    union { float f; unsigned int i; } c; c.f = x;
    unsigned int r = c.i + 0x7FFFu + ((c.i >> 16) & 1u);   // RNE
    return (unsigned short)(r >> 16);
}
__device__ __forceinline__ unsigned char f2fp8(float x) {
    int p = __builtin_amdgcn_cvt_pk_fp8_f32(x, x, 0, false);
    return (unsigned char)(p & 0xFF);
}
__device__ __forceinline__ float2v up8lo(unsigned int w) {
    return __builtin_amdgcn_cvt_pk_f32_fp8(w, false);
}
__device__ __forceinline__ float2v up8hi(unsigned int w) {
    return __builtin_amdgcn_cvt_pk_f32_fp8(w, true);
}

__global__ void k_prepW2(const float* __restrict__ W1, const float* __restrict__ W2,
                         unsigned short* __restrict__ Wt1, unsigned short* __restrict__ Wt2) {
    const float* W = blockIdx.x ? W2 : W1;
    unsigned short* Wt = blockIdx.x ? Wt2 : Wt1;
    for (int i = threadIdx.x; i < 64 * 64; i += 256) {
        int n = i >> 6, k = i & 63;
        Wt[i] = f2bf(W[k * 64 + n]);
    }
}

__global__ void k_zeroCur(Ctx c0, Ctx c1, int nb0, int K) {
    int b = blockIdx.x; Ctx c = c0;
    if (b >= nb0) { c = c1; b -= nb0; }
    int i = b * blockDim.x + threadIdx.x;
    if (i < K) c.cursorG[i * CPAD] = 0;
}

// binA v2: LDS counting sort per block, then burst-write each bucket run.
// LDS: cnt/ofs/segBase 3x4KB + sorted 32KB + bkt 16KB = 60KB (2 blocks/CU).
__global__ __launch_bounds__(256) void k_binA(Ctx c0, Ctx c1, int nb0, int E, int K) {
    __shared__ int cnt[KMAX];
    __shared__ int ofs[KMAX];
    __shared__ int segBase[KMAX];
    __shared__ unsigned int sorted[EPB];
    __shared__ unsigned short bkt[EPB];
    int b = blockIdx.x; Ctx c = c0;
    if (b >= nb0) { c = c1; b -= nb0; }
    int tid = threadIdx.x;
    for (int j = tid; j < KMAX; j += 256) cnt[j] = 0;
    __syncthreads();
    int base = b * EPB;
    int tot = E - base; if (tot > EPB) tot = EPB;
    // pass 1: count
    for (int k = 0; k < EPB / 256; ++k) {
        int e = base + k * 256 + tid;
        if (e < E) atomicAdd(&cnt[c.edst[e] >> SHIFT], 1);
    }
    __syncthreads();
    // exclusive scan cnt -> ofs (KMAX elems, 4 per thread; segBase = scratch)
    int j4 = tid * 4;
    int s0 = cnt[j4], s1 = cnt[j4 + 1], s2 = cnt[j4 + 2], s3 = cnt[j4 + 3];
    int tsum = s0 + s1 + s2 + s3;
    segBase[tid] = tsum;
    __syncthreads();
#pragma unroll
    for (int off = 1; off < 256; off <<= 1) {
        int t = (tid >= off) ? segBase[tid - off] : 0;
        __syncthreads();
        segBase[tid] += t;
        __syncthreads();
    }
    int excl = segBase[tid] - tsum;
    ofs[j4] = excl;
    ofs[j4 + 1] = excl + s0;
    ofs[j4 + 2] = excl + s0 + s1;
    ofs[j4 + 3] = excl + s0 + s1 + s2;
    __syncthreads();
    // reserve global segments; reset cnt as scatter cursor
    for (int j = tid; j < K; j += 256) {
        int cc = cnt[j];
        segBase[j] = cc ? atomicAdd(&c.cursorG[j * CPAD], cc) : 0;
        cnt[j] = 0;
    }
    __syncthreads();
    // pass 2: scatter into LDS sorted order (edges re-read, L2-hot)
    for (int k = 0; k < EPB / 256; ++k) {
        int e = base + k * 256 + tid;
        if (e < E) {
            int d = c.edst[e];
            int bk = d >> SHIFT;
            int r = atomicAdd(&cnt[bk], 1);
            int p = ofs[bk] + r;
            sorted[p] = ((unsigned int)(d & (CHUNK - 1)) << 17) | (unsigned int)c.esrc[e];
            bkt[p] = (unsigned short)bk;
        }
    }
    __syncthreads();
    // output: consecutive p -> contiguous run per bucket -> lines filled hot
    for (int p = tid; p < tot; p += 256) {
        unsigned int v = sorted[p];
        int bk = bkt[p];
        int pos = segBase[bk] + (p - ofs[bk]);
        if (pos < CAP) c.temp[(size_t)bk * CAP + pos] = v;
    }
}

__global__ __launch_bounds__(1024) void k_scanK(Ctx c0, Ctx c1, int K, int N, int E) {
    Ctx c = blockIdx.x ? c1 : c0;
    __shared__ int s[1024];
    int tid = threadIdx.x;
    int v = (tid < K) ? c.cursorG[tid * CPAD] : 0;
    s[tid] = v;
    __syncthreads();
#pragma unroll
    for (int off = 1; off < 1024; off <<= 1) {
        int t = (tid >= off) ? s[tid - off] : 0;
        __syncthreads();
        s[tid] += t;
        __syncthreads();
    }
    if (tid < K) c.bucketBase[tid] = s[tid] - v;
    if (tid == 0) c.row_ptr[N] = E;
}

// Per-bucket LDS counting sort -> contiguous csr slice + row_ptr + dinv.
__global__ __launch_bounds__(256) void k_csrb(Ctx c0, Ctx c1, int nb0, int N) {
    __shared__ int deg[CHUNK];
    __shared__ int lofs[CHUNK];
    __shared__ int cur[CHUNK];
    int b = blockIdx.x; Ctx c = c0;
    if (b >= nb0) { c = c1; b -= nb0; }
    int tid = threadIdx.x;
    if (tid < CHUNK) deg[tid] = 0;
    __syncthreads();
    int cnt = c.cursorG[b * CPAD]; if (cnt > CAP) cnt = CAP;
    const size_t tb = (size_t)b * CAP;
    for (int i = tid; i < cnt; i += 256) atomicAdd(&deg[c.temp[tb + i] >> 17], 1);
    __syncthreads();
    if (tid < CHUNK) lofs[tid] = deg[tid];
    __syncthreads();
#pragma unroll
    for (int off = 1; off < CHUNK; off <<= 1) {
        int t = (tid < CHUNK && tid >= off) ? lofs[tid - off] : 0;
        __syncthreads();
        if (tid < CHUNK) lofs[tid] += t;
        __syncthreads();
    }
    int base = c.bucketBase[b];
    if (tid < CHUNK) {
        int excl = lofs[tid] - deg[tid];
        lofs[tid] = excl;
        cur[tid] = 0;
        int node = b * CHUNK + tid;
        if (node < N) {
            c.row_ptr[node] = base + excl;
            c.dinv[node] = rsqrtf((float)deg[tid] + 1.0f);
        }
    }
    __syncthreads();
    for (int i = tid; i < cnt; i += 256) {
        unsigned int p = c.temp[tb + i];
        int dl = p >> 17;
        int rank = atomicAdd(&cur[dl], 1);
        c.csr[base + lofs[dl] + rank] = (int)(p & 0x1FFFFu);
    }
}

// Shared MFMA body: A-fragments provided; B from Wt; store fp8 Hs.
__device__ __forceinline__ void mfma_tail(short8 a0, short8 a1,
                                          const unsigned short* __restrict__ Wt,
                                          unsigned char* __restrict__ Hs,
                                          int row0, int r, int q, int N) {
    short8 bfrag[4][2];
#pragma unroll
    for (int ct = 0; ct < 4; ++ct)
#pragma unroll
        for (int kb = 0; kb < 2; ++kb)
            bfrag[ct][kb] = *(const short8*)(Wt + (ct * 16 + r) * 64 + q * 8 + 32 * kb);
    f32x4 acc[4];
#pragma unroll
    for (int ct = 0; ct < 4; ++ct) {
        acc[ct] = (f32x4){0.0f, 0.0f, 0.0f, 0.0f};
        acc[ct] = __builtin_amdgcn_mfma_f32_16x16x32_bf16(a0, bfrag[ct][0], acc[ct], 0, 0, 0);
        acc[ct] = __builtin_amdgcn_mfma_f32_16x16x32_bf16(a1, bfrag[ct][1], acc[ct], 0, 0, 0);
    }
#pragma unroll
    for (int reg = 0; reg < 4; ++reg) {
        int row = row0 + q * 4 + reg;
        if (row < N) {
            size_t base = (size_t)row * 64 + r;
#pragma unroll
            for (int ct = 0; ct < 4; ++ct)
                Hs[base + ct * 16] = f2fp8(acc[ct][reg]);
        }
    }
}

// GEMM1: fp32 X in, dinv folded into A-fragment conversion.
__global__ __launch_bounds__(256) void k_gemm1(Ctx c0, Ctx c1, int nb0,
                                               const unsigned short* __restrict__ Wt,
                                               int nTiles, int N) {
    int b = blockIdx.x; Ctx c = c0;
    if (b >= nb0) { c = c1; b -= nb0; }
    int wave = threadIdx.x >> 6, lane = threadIdx.x & 63;
    int tile = b * 4 + wave;
    if (tile >= nTiles) return;
    int r = lane & 15, q = lane >> 4;
    int row0 = tile * 16;
    int row = row0 + r;
    int rr = row < N ? row : N - 1;
    float d = c.dinv[rr];
    const float* xrow = c.X + (size_t)rr * 64 + q * 8;
    short8 a0, a1;
#pragma unroll
    for (int j = 0; j < 8; ++j) a0[j] = (short)f2bf(xrow[j] * d);
#pragma unroll
    for (int j = 0; j < 8; ++j) a1[j] = (short)f2bf(xrow[32 + j] * d);
    mfma_tail(a0, a1, Wt, c.Hs, row0, r, q, N);
}

// GEMM2: bf16 Ab in (already dinv-scaled by aggregate1).
__global__ __launch_bounds__(256) void k_gemm2(Ctx c0, Ctx c1, int nb0,
                                               const unsigned short* __restrict__ Wt,
                                               int nTiles, int N) {
    int b = blockIdx.x; Ctx c = c0;
    if (b >= nb0) { c = c1; b -= nb0; }
    int wave = threadIdx.x >> 6, lane = threadIdx.x & 63;
    int tile = b * 4 + wave;
    if (tile >= nTiles) return;
    int r = lane & 15, q = lane >> 4;
    int row0 = tile * 16;
    const unsigned short* xrow = c.Ab + (size_t)(row0 + r) * 64 + q * 8;
    short8 a0 = *(const short8*)(xrow);
    short8 a1 = *(const short8*)(xrow + 32);
    mfma_tail(a0, a1, Wt, c.Hs, row0, r, q, N);
}

// 2 nodes per wave: half h (lane>>5) owns one node; 2 groups x 16 lanes per
// half; lane s covers fp8 channels 4s..4s+3 (one dword; 64B row per group).
__device__ __forceinline__ void agg_node2(const unsigned char* __restrict__ Hs,
                                          const int* __restrict__ csr,
                                          int beg, int deg, int maxd, int lane,
                                          float2v* acc) {
    int hbase = lane & 32;
    int hl = lane & 31;
    int g = (lane >> 4) & 1;
    int s = lane & 15;
    for (int base = 0; base < maxd; base += 32) {
        int idx = (base + hl < deg) ? csr[beg + base + hl] : 0;   // coalesced/half
        int mW = maxd - base; if (mW > 32) mW = 32;               // wave-uniform
        for (int t = 0; t < mW; t += 4) {
            int s0 = __shfl(idx, hbase + t + g, 64);              // exec-uniform
            int s1 = __shfl(idx, hbase + t + 2 + g, 64);
            if (base + t + g < deg) {
                unsigned int h0 = *(const unsigned int*)(Hs + (size_t)s0 * 64 + s * 4);
                acc[0] += up8lo(h0); acc[1] += up8hi(h0);
            }
            if (base + t + 2 + g < deg) {
                unsigned int h1 = *(const unsigned int*)(Hs + (size_t)s1 * 64 + s * 4);
                acc[0] += up8lo(h1); acc[1] += up8hi(h1);
            }
        }
    }
    // merge the half's 2 groups (bit 4); does not cross halves
#pragma unroll
    for (int k = 0; k < 2; ++k) {
        float2v o;
        o.x = __shfl_xor(acc[k].x, 16, 64); o.y = __shfl_xor(acc[k].y, 16, 64);
        acc[k] += o;
    }
}

// layer-1: Ab[d, f] = bf16( dinv[d] * relu(b[f] + dinv[d] * agg) )
__global__ __launch_bounds__(256) void k_agg1(Ctx c0, Ctx c1, int nb0,
                                              const float* __restrict__ bias, int n) {
    int b = blockIdx.x; Ctx c = c0;
    if (b >= nb0) { c = c1; b -= nb0; }
    int wave = threadIdx.x >> 6, lane = threadIdx.x & 63;
    int h = lane >> 5;
    int node = b * 8 + wave * 2 + h;
    int nd = node < n ? node : 0;
    int beg = c.row_ptr[nd];
    int deg = (node < n) ? (c.row_ptr[nd + 1] - beg) : 0;
    int od = __shfl_xor(deg, 32, 64);
    int maxd = deg > od ? deg : od;      // wave-uniform
    float2v acc[2] = {{0.f, 0.f}, {0.f, 0.f}};
    agg_node2(c.Hs, c.csr, beg, deg, maxd, lane, acc);
    if (((lane >> 4) & 1) == 0 && node < n) {
        int s = lane & 15;
        unsigned int hv = *(const unsigned int*)(c.Hs + (size_t)node * 64 + s * 4);
        float2v h0 = up8lo(hv), h1 = up8hi(hv);
        float4 bb = *(const float4*)(bias + s * 4);
        float d = c.dinv[node];
        float v0 = fmaxf(bb.x + d * (acc[0].x + h0.x), 0.0f) * d;
        float v1 = fmaxf(bb.y + d * (acc[0].y + h0.y), 0.0f) * d;
        float v2 = fmaxf(bb.z + d * (acc[1].x + h1.x), 0.0f) * d;
        float v3 = fmaxf(bb.w + d * (acc[1].y + h1.y), 0.0f) * d;
        ushort4 o;
        o.x = f2bf(v0); o.y = f2bf(v1); o.z = f2bf(v2); o.w = f2bf(v3);
        *(ushort4*)(c.Ab + (size_t)node * 64 + s * 4) = o;
    }
}

// layer-2: block-reduce 8 relu'd rows -> P[block, f]
__global__ __launch_bounds__(256) void k_agg2(Ctx c0, Ctx c1, int nb0,
                                              const float* __restrict__ bias, int n) {
    __shared__ float red[8 * 64];
    int b = blockIdx.x; Ctx c = c0;
    if (b >= nb0) { c = c1; b -= nb0; }
    int wave = threadIdx.x >> 6, lane = threadIdx.x & 63;
    int h = lane >> 5;
    int node = b * 8 + wave * 2 + h;
    int nd = node < n ? node : 0;
    int beg = c.row_ptr[nd];
    int deg = (node < n) ? (c.row_ptr[nd + 1] - beg) : 0;
    int od = __shfl_xor(deg, 32, 64);
    int maxd = deg > od ? deg : od;
    float2v acc[2] = {{0.f, 0.f}, {0.f, 0.f}};
    agg_node2(c.Hs, c.csr, beg, deg, maxd, lane, acc);
    if (((lane >> 4) & 1) == 0) {
        int s = lane & 15;
        float4 v = {0.f, 0.f, 0.f, 0.f};
        if (node < n) {
            unsigned int hv = *(const unsigned int*)(c.Hs + (size_t)node * 64 + s * 4);
            float2v h0 = up8lo(hv), h1 = up8hi(hv);
            float4 bb = *(const float4*)(bias + s * 4);
            float d = c.dinv[node];
            v.x = fmaxf(bb.x + d * (acc[0].x + h0.x), 0.0f);
            v.y = fmaxf(bb.y + d * (acc[0].y + h0.y), 0.0f);
            v.z = fmaxf(bb.z + d * (acc[1].x + h1.x), 0.0f);
            v.w = fmaxf(bb.w + d * (acc[1].y + h1.y), 0.0f);
        }
        *(float4*)(&red[(wave * 2 + h) * 64 + s * 4]) = v;
    }
    __syncthreads();
    if (threadIdx.x < 64) {
        float acc8 = 0.0f;
#pragma unroll
        for (int r = 0; r < 8; ++r) acc8 += red[r * 64 + threadIdx.x];
        c.P[(size_t)b * 64 + threadIdx.x] = acc8;
    }
}

// colsum -> per-block partials in P2 (no atomics, no zero pass)
__global__ void k_colsum(Ctx c0, Ctx c1, int nb0, int rows) {
    int b = blockIdx.x; Ctx c = c0;
    if (b >= nb0) { c = c1; b -= nb0; }
    int f = threadIdx.x;  // 64
    float acc = 0.0f;
    for (int r = b; r < rows; r += nb0) acc += c.P[(size_t)r * 64 + f];
    c.P2[b * 64 + f] = acc;
}

// single-wave FC: reduce 256 partial rows, then out = fcb + (S/n) @ fcw^T
__global__ void k_fc(Ctx c0, Ctx c1, const float* __restrict__ fcw,
                     const float* __restrict__ fcb, int n) {
    Ctx c = blockIdx.x ? c1 : c0;
    __shared__ float S[64];
    int j = threadIdx.x;  // 64
    float s = 0.0f;
    for (int r = 0; r < 256; ++r) s += c.P2[r * 64 + j];
    S[j] = s;
    __syncthreads();
    float inv = 1.0f / (float)n;
    float acc = fcb[j];
#pragma unroll
    for (int k = 0; k < 64; ++k) acc += (S[k] * inv) * fcw[j * 64 + k];
    c.outp[j] = acc;
}

extern "C" void kernel_launch(void* const* d_in, const int* in_sizes, int n_in,
                              void* d_out, int out_size, void* d_ws, size_t ws_size,
                              hipStream_t stream) {
    const float* x[2]  = {(const float*)d_in[0], (const float*)d_in[1]};
    const int*   ei[2] = {(const int*)d_in[2], (const int*)d_in[3]};
    const float* W1  = (const float*)d_in[4];
    const float* b1  = (const float*)d_in[5];
    const float* W2  = (const float*)d_in[6];
    const float* b2  = (const float*)d_in[7];
    const float* fcw = (const float*)d_in[8];
    const float* fcb = (const float*)d_in[9];
    float* out = (float*)d_out;

    const int N  = in_sizes[0] / 64;
    const int E  = in_sizes[2] / 2;
    const int NF = N * 64;
    const int K  = (N + CHUNK - 1) / CHUNK;     // 782 buckets
    const int gGm = (N + 7) / 8;                // aggregate blocks (8 nodes each)
    const int nTiles = (N + 15) / 16;
    const int gMf = (nTiles + 3) / 4;
    const int gBin = (E + EPB - 1) / EPB;
    const int gK  = (K + TPB - 1) / TPB;

    auto al = [](size_t x) { return (x + 127) & ~(size_t)127; };
    size_t tempB = (size_t)K * CAP * 4;
    size_t abB   = ((size_t)NF + 64) * 2;
    size_t szRegion = al(tempB > abB ? tempB : abB);   // Ab aliases temp
    size_t szHs  = al((size_t)NF + 64);                // fp8: 1 B/elem
    size_t szCsr = al((size_t)E * 4);
    size_t szRp  = al((size_t)(N + 1) * 4);
    size_t szDi  = al((size_t)N * 4);
    size_t szCu  = al((size_t)K * CPAD * 4);           // padded cursors
    size_t szBB  = al((size_t)K * 4);
    size_t szP   = al((size_t)gGm * 64 * 4);
    size_t szP2  = al((size_t)256 * 64 * 4);
    size_t setB  = szRegion + szHs + szCsr + szRp + szDi + szCu + szBB + szP + szP2;
    size_t wtB   = 2 * al(64 * 64 * 2);
    bool batched = ws_size >= wtB + 2 * setB;

    char* base = (char*)d_ws;
    unsigned short* Wt1 = (unsigned short*)base;
    unsigned short* Wt2 = (unsigned short*)(base + al(64 * 64 * 2));

    auto mkctx = [&](int g, char* p) {
        Ctx c;
        c.X = x[g]; c.esrc = ei[g]; c.edst = ei[g] + E;
        c.temp = (unsigned int*)p; c.Ab = (unsigned short*)p; p += szRegion;
        c.Hs = (unsigned char*)p; p += szHs;
        c.csr = (int*)p; p += szCsr;
        c.row_ptr = (int*)p; p += szRp;
        c.dinv = (float*)p; p += szDi;
        c.cursorG = (int*)p; p += szCu;
        c.bucketBase = (int*)p; p += szBB;
        c.P = (float*)p; p += szP;
        c.P2 = (float*)p;
        c.outp = out + g * 64;
        return c;
    };
    char* set0 = base + wtB;
    Ctx c0 = mkctx(0, set0);
    Ctx c1 = mkctx(1, batched ? set0 + setB : set0);   // fallback: shares set0

    k_prepW2<<<2, 256, 0, stream>>>(W1, W2, Wt1, Wt2);

    auto pipe = [&](Ctx A, Ctx B, int mult) {
        k_zeroCur<<<mult * gK, TPB, 0, stream>>>(A, B, gK, K);
        k_binA<<<mult * gBin, 256, 0, stream>>>(A, B, gBin, E, K);
        k_scanK<<<mult, 1024, 0, stream>>>(A, B, K, N, E);
        k_csrb<<<mult * K, 256, 0, stream>>>(A, B, K, N);
        k_gemm1<<<mult * gMf, 256, 0, stream>>>(A, B, gMf, Wt1, nTiles, N);
        k_agg1<<<mult * gGm, 256, 0, stream>>>(A, B, gGm, b1, N);
        k_gemm2<<<mult * gMf, 256, 0, stream>>>(A, B, gMf, Wt2, nTiles, N);
        k_agg2<<<mult * gGm, 256, 0, stream>>>(A, B, gGm, b2, N);
        k_colsum<<<mult * 256, 64, 0, stream>>>(A, B, 256, gGm);
        k_fc<<<mult, 64, 0, stream>>>(A, B, fcw, fcb, N);
    };

    if (batched) {
        pipe(c0, c1, 2);
    } else {
        pipe(c0, c0, 1);   // sequential, shared buffer set
        pipe(c1, c1, 1);
    }
}

// Round 16
// 344.547 us; speedup vs baseline: 1.2676x; 1.1402x over previous
//
#include <hip/hip_runtime.h>

// SiameseGNN round 16: 8-deep gather pipeline in the aggregate (MLP fix).
//
// R10-R15 evidence chain: aggregate pinned 76-86us across instruction cuts
// (VALU 71->44%) and byte cuts (bf16->fp8). Final model: 800K 4-row VMEM
// instrs, ~2 gathers in flight per wave (loop issues 2 loads then consumes)
// -> ~50 outstanding lines/CU at ~550cyc latency == measured 42 Gline/s.
// MLP-limited. Fix: 16-edge bursts -- 8 UNCONDITIONAL gathers back-to-back
// (invalid slots resolve to row 0 via idx=0 fallback: address always valid,
// L1-hot), then 8 cndmask-masked consumes (fp8 0x0 = +0.0). No divergent
// exec branches around loads -> compiler keeps vmcnt depth 8.
// Everything else unchanged from R15 (LDS-sort binA, fp8 rows, batching).

#define TPB    256
#define CHUNK  128
#define SHIFT  7
#define KMAX   1024
#define CAP    2560
#define EPB    8192
#define CPAD   16      // cursorG stride (ints)

typedef __attribute__((ext_vector_type(8))) short short8;
typedef __attribute__((ext_vector_type(4))) float f32x4;
typedef __attribute__((ext_vector_type(2))) float float2v;

struct Ctx {
    const float* X; const int* esrc; const int* edst;
    unsigned int* temp; unsigned short* Ab; unsigned char* Hs;
    int* csr; int* row_ptr; float* dinv; int* cursorG; int* bucketBase;
    float* P; float* P2; float* outp;
};

__device__ __forceinline__ unsigned short f2bf(float x) {
    union { float f; unsigned int i; } c; c.f = x;
    unsigned int r = c.i + 0x7FFFu + ((c.i >> 16) & 1u);   // RNE
    return (unsigned short)(r >> 16);
}
__device__ __forceinline__ unsigned char f2fp8(float x) {
    int p = __builtin_amdgcn_cvt_pk_fp8_f32(x, x, 0, false);
    return (unsigned char)(p & 0xFF);
}
__device__ __forceinline__ float2v up8lo(unsigned int w) {
    return __builtin_amdgcn_cvt_pk_f32_fp8(w, false);
}
__device__ __forceinline__ float2v up8hi(unsigned int w) {
    return __builtin_amdgcn_cvt_pk_f32_fp8(w, true);
}

__global__ void k_prepW2(const float* __restrict__ W1, const float* __restrict__ W2,
                         unsigned short* __restrict__ Wt1, unsigned short* __restrict__ Wt2) {
    const float* W = blockIdx.x ? W2 : W1;
    unsigned short* Wt = blockIdx.x ? Wt2 : Wt1;
    for (int i = threadIdx.x; i < 64 * 64; i += 256) {
        int n = i >> 6, k = i & 63;
        Wt[i] = f2bf(W[k * 64 + n]);
    }
}

__global__ void k_zeroCur(Ctx c0, Ctx c1, int nb0, int K) {
    int b = blockIdx.x; Ctx c = c0;
    if (b >= nb0) { c = c1; b -= nb0; }
    int i = b * blockDim.x + threadIdx.x;
    if (i < K) c.cursorG[i * CPAD] = 0;
}

// binA: LDS counting sort per block, then burst-write each bucket run.
__global__ __launch_bounds__(256) void k_binA(Ctx c0, Ctx c1, int nb0, int E, int K) {
    __shared__ int cnt[KMAX];
    __shared__ int ofs[KMAX];
    __shared__ int segBase[KMAX];
    __shared__ unsigned int sorted[EPB];
    __shared__ unsigned short bkt[EPB];
    int b = blockIdx.x; Ctx c = c0;
    if (b >= nb0) { c = c1; b -= nb0; }
    int tid = threadIdx.x;
    for (int j = tid; j < KMAX; j += 256) cnt[j] = 0;
    __syncthreads();
    int base = b * EPB;
    int tot = E - base; if (tot > EPB) tot = EPB;
    for (int k = 0; k < EPB / 256; ++k) {
        int e = base + k * 256 + tid;
        if (e < E) atomicAdd(&cnt[c.edst[e] >> SHIFT], 1);
    }
    __syncthreads();
    int j4 = tid * 4;
    int s0 = cnt[j4], s1 = cnt[j4 + 1], s2 = cnt[j4 + 2], s3 = cnt[j4 + 3];
    int tsum = s0 + s1 + s2 + s3;
    segBase[tid] = tsum;
    __syncthreads();
#pragma unroll
    for (int off = 1; off < 256; off <<= 1) {
        int t = (tid >= off) ? segBase[tid - off] : 0;
        __syncthreads();
        segBase[tid] += t;
        __syncthreads();
    }
    int excl = segBase[tid] - tsum;
    ofs[j4] = excl;
    ofs[j4 + 1] = excl + s0;
    ofs[j4 + 2] = excl + s0 + s1;
    ofs[j4 + 3] = excl + s0 + s1 + s2;
    __syncthreads();
    for (int j = tid; j < K; j += 256) {
        int cc = cnt[j];
        segBase[j] = cc ? atomicAdd(&c.cursorG[j * CPAD], cc) : 0;
        cnt[j] = 0;
    }
    __syncthreads();
    for (int k = 0; k < EPB / 256; ++k) {
        int e = base + k * 256 + tid;
        if (e < E) {
            int d = c.edst[e];
            int bk = d >> SHIFT;
            int r = atomicAdd(&cnt[bk], 1);
            int p = ofs[bk] + r;
            sorted[p] = ((unsigned int)(d & (CHUNK - 1)) << 17) | (unsigned int)c.esrc[e];
            bkt[p] = (unsigned short)bk;
        }
    }
    __syncthreads();
    for (int p = tid; p < tot; p += 256) {
        unsigned int v = sorted[p];
        int bk = bkt[p];
        int pos = segBase[bk] + (p - ofs[bk]);
        if (pos < CAP) c.temp[(size_t)bk * CAP + pos] = v;
    }
}

__global__ __launch_bounds__(1024) void k_scanK(Ctx c0, Ctx c1, int K, int N, int E) {
    Ctx c = blockIdx.x ? c1 : c0;
    __shared__ int s[1024];
    int tid = threadIdx.x;
    int v = (tid < K) ? c.cursorG[tid * CPAD] : 0;
    s[tid] = v;
    __syncthreads();
#pragma unroll
    for (int off = 1; off < 1024; off <<= 1) {
        int t = (tid >= off) ? s[tid - off] : 0;
        __syncthreads();
        s[tid] += t;
        __syncthreads();
    }
    if (tid < K) c.bucketBase[tid] = s[tid] - v;
    if (tid == 0) c.row_ptr[N] = E;
}

// Per-bucket LDS counting sort -> contiguous csr slice + row_ptr + dinv.
__global__ __launch_bounds__(256) void k_csrb(Ctx c0, Ctx c1, int nb0, int N) {
    __shared__ int deg[CHUNK];
    __shared__ int lofs[CHUNK];
    __shared__ int cur[CHUNK];
    int b = blockIdx.x; Ctx c = c0;
    if (b >= nb0) { c = c1; b -= nb0; }
    int tid = threadIdx.x;
    if (tid < CHUNK) deg[tid] = 0;
    __syncthreads();
    int cnt = c.cursorG[b * CPAD]; if (cnt > CAP) cnt = CAP;
    const size_t tb = (size_t)b * CAP;
    for (int i = tid; i < cnt; i += 256) atomicAdd(&deg[c.temp[tb + i] >> 17], 1);
    __syncthreads();
    if (tid < CHUNK) lofs[tid] = deg[tid];
    __syncthreads();
#pragma unroll
    for (int off = 1; off < CHUNK; off <<= 1) {
        int t = (tid < CHUNK && tid >= off) ? lofs[tid - off] : 0;
        __syncthreads();
        if (tid < CHUNK) lofs[tid] += t;
        __syncthreads();
    }
    int base = c.bucketBase[b];
    if (tid < CHUNK) {
        int excl = lofs[tid] - deg[tid];
        lofs[tid] = excl;
        cur[tid] = 0;
        int node = b * CHUNK + tid;
        if (node < N) {
            c.row_ptr[node] = base + excl;
            c.dinv[node] = rsqrtf((float)deg[tid] + 1.0f);
        }
    }
    __syncthreads();
    for (int i = tid; i < cnt; i += 256) {
        unsigned int p = c.temp[tb + i];
        int dl = p >> 17;
        int rank = atomicAdd(&cur[dl], 1);
        c.csr[base + lofs[dl] + rank] = (int)(p & 0x1FFFFu);
    }
}

// Shared MFMA body: A-fragments provided; B from Wt; store fp8 Hs.
__device__ __forceinline__ void mfma_tail(short8 a0, short8 a1,
                                          const unsigned short* __restrict__ Wt,
                                          unsigned char* __restrict__ Hs,
                                          int row0, int r, int q, int N) {
    short8 bfrag[4][2];
#pragma unroll
    for (int ct = 0; ct < 4; ++ct)
#pragma unroll
        for (int kb = 0; kb < 2; ++kb)
            bfrag[ct][kb] = *(const short8*)(Wt + (ct * 16 + r) * 64 + q * 8 + 32 * kb);
    f32x4 acc[4];
#pragma unroll
    for (int ct = 0; ct < 4; ++ct) {
        acc[ct] = (f32x4){0.0f, 0.0f, 0.0f, 0.0f};
        acc[ct] = __builtin_amdgcn_mfma_f32_16x16x32_bf16(a0, bfrag[ct][0], acc[ct], 0, 0, 0);
        acc[ct] = __builtin_amdgcn_mfma_f32_16x16x32_bf16(a1, bfrag[ct][1], acc[ct], 0, 0, 0);
    }
#pragma unroll
    for (int reg = 0; reg < 4; ++reg) {
        int row = row0 + q * 4 + reg;
        if (row < N) {
            size_t base = (size_t)row * 64 + r;
#pragma unroll
            for (int ct = 0; ct < 4; ++ct)
                Hs[base + ct * 16] = f2fp8(acc[ct][reg]);
        }
    }
}

// GEMM1: fp32 X in, dinv folded into A-fragment conversion.
__global__ __launch_bounds__(256) void k_gemm1(Ctx c0, Ctx c1, int nb0,
                                               const unsigned short* __restrict__ Wt,
                                               int nTiles, int N) {
    int b = blockIdx.x; Ctx c = c0;
    if (b >= nb0) { c = c1; b -= nb0; }
    int wave = threadIdx.x >> 6, lane = threadIdx.x & 63;
    int tile = b * 4 + wave;
    if (tile >= nTiles) return;
    int r = lane & 15, q = lane >> 4;
    int row0 = tile * 16;
    int row = row0 + r;
    int rr = row < N ? row : N - 1;
    float d = c.dinv[rr];
    const float* xrow = c.X + (size_t)rr * 64 + q * 8;
    short8 a0, a1;
#pragma unroll
    for (int j = 0; j < 8; ++j) a0[j] = (short)f2bf(xrow[j] * d);
#pragma unroll
    for (int j = 0; j < 8; ++j) a1[j] = (short)f2bf(xrow[32 + j] * d);
    mfma_tail(a0, a1, Wt, c.Hs, row0, r, q, N);
}

// GEMM2: bf16 Ab in (already dinv-scaled by aggregate1).
__global__ __launch_bounds__(256) void k_gemm2(Ctx c0, Ctx c1, int nb0,
                                               const unsigned short* __restrict__ Wt,
                                               int nTiles, int N) {
    int b = blockIdx.x; Ctx c = c0;
    if (b >= nb0) { c = c1; b -= nb0; }
    int wave = threadIdx.x >> 6, lane = threadIdx.x & 63;
    int tile = b * 4 + wave;
    if (tile >= nTiles) return;
    int r = lane & 15, q = lane >> 4;
    int row0 = tile * 16;
    const unsigned short* xrow = c.Ab + (size_t)(row0 + r) * 64 + q * 8;
    short8 a0 = *(const short8*)(xrow);
    short8 a1 = *(const short8*)(xrow + 32);
    mfma_tail(a0, a1, Wt, c.Hs, row0, r, q, N);
}

// 2 nodes per wave; per half: 2 groups x 16 lanes, lane s covers fp8
// channels 4s..4s+3. 16-edge bursts: 8 unconditional gathers (invalid
// slots -> row 0, L1-hot) then 8 masked consumes -- vmcnt depth 8.
__device__ __forceinline__ void agg_node2(const unsigned char* __restrict__ Hs,
                                          const int* __restrict__ csr,
                                          int beg, int deg, int maxd, int lane,
                                          float2v* acc) {
    int hbase = lane & 32;
    int hl = lane & 31;
    int g = (lane >> 4) & 1;
    int s = lane & 15;
    for (int base = 0; base < maxd; base += 32) {
        int idx = (base + hl < deg) ? csr[beg + base + hl] : 0;   // coalesced/half
        int mW = maxd - base; if (mW > 32) mW = 32;               // wave-uniform
        for (int t = 0; t < mW; t += 16) {                        // 16-edge burst
            unsigned int h[8];
            bool valid[8];
#pragma unroll
            for (int u = 0; u < 8; ++u) {                         // issue phase
                int slot = t + 2 * u + g;                         // <= 31
                int su = __shfl(idx, hbase + slot, 64);           // exec-uniform
                h[u] = *(const unsigned int*)(Hs + (size_t)su * 64 + s * 4);
                valid[u] = (base + slot < deg);
            }
#pragma unroll
            for (int u = 0; u < 8; ++u) {                         // consume phase
                unsigned int w = valid[u] ? h[u] : 0u;            // cndmask; fp8 0 = +0.0
                acc[0] += up8lo(w); acc[1] += up8hi(w);
            }
        }
    }
    // merge the half's 2 groups (bit 4); does not cross halves
#pragma unroll
    for (int k = 0; k < 2; ++k) {
        float2v o;
        o.x = __shfl_xor(acc[k].x, 16, 64); o.y = __shfl_xor(acc[k].y, 16, 64);
        acc[k] += o;
    }
}

// layer-1: Ab[d, f] = bf16( dinv[d] * relu(b[f] + dinv[d] * agg) )
__global__ __launch_bounds__(256) void k_agg1(Ctx c0, Ctx c1, int nb0,
                                              const float* __restrict__ bias, int n) {
    int b = blockIdx.x; Ctx c = c0;
    if (b >= nb0) { c = c1; b -= nb0; }
    int wave = threadIdx.x >> 6, lane = threadIdx.x & 63;
    int h = lane >> 5;
    int node = b * 8 + wave * 2 + h;
    int nd = node < n ? node : 0;
    int beg = c.row_ptr[nd];
    int deg = (node < n) ? (c.row_ptr[nd + 1] - beg) : 0;
    int od = __shfl_xor(deg, 32, 64);
    int maxd = deg > od ? deg : od;      // wave-uniform
    float2v acc[2] = {{0.f, 0.f}, {0.f, 0.f}};
    agg_node2(c.Hs, c.csr, beg, deg, maxd, lane, acc);
    if (((lane >> 4) & 1) == 0 && node < n) {
        int s = lane & 15;
        unsigned int hv = *(const unsigned int*)(c.Hs + (size_t)node * 64 + s * 4);
        float2v h0 = up8lo(hv), h1 = up8hi(hv);
        float4 bb = *(const float4*)(bias + s * 4);
        float d = c.dinv[node];
        float v0 = fmaxf(bb.x + d * (acc[0].x + h0.x), 0.0f) * d;
        float v1 = fmaxf(bb.y + d * (acc[0].y + h0.y), 0.0f) * d;
        float v2 = fmaxf(bb.z + d * (acc[1].x + h1.x), 0.0f) * d;
        float v3 = fmaxf(bb.w + d * (acc[1].y + h1.y), 0.0f) * d;
        ushort4 o;
        o.x = f2bf(v0); o.y = f2bf(v1); o.z = f2bf(v2); o.w = f2bf(v3);
        *(ushort4*)(c.Ab + (size_t)node * 64 + s * 4) = o;
    }
}

// layer-2: block-reduce 8 relu'd rows -> P[block, f]
__global__ __launch_bounds__(256) void k_agg2(Ctx c0, Ctx c1, int nb0,
                                              const float* __restrict__ bias, int n) {
    __shared__ float red[8 * 64];
    int b = blockIdx.x; Ctx c = c0;
    if (b >= nb0) { c = c1; b -= nb0; }
    int wave = threadIdx.x >> 6, lane = threadIdx.x & 63;
    int h = lane >> 5;
    int node = b * 8 + wave * 2 + h;
    int nd = node < n ? node : 0;
    int beg = c.row_ptr[nd];
    int deg = (node < n) ? (c.row_ptr[nd + 1] - beg) : 0;
    int od = __shfl_xor(deg, 32, 64);
    int maxd = deg > od ? deg : od;
    float2v acc[2] = {{0.f, 0.f}, {0.f, 0.f}};
    agg_node2(c.Hs, c.csr, beg, deg, maxd, lane, acc);
    if (((lane >> 4) & 1) == 0) {
        int s = lane & 15;
        float4 v = {0.f, 0.f, 0.f, 0.f};
        if (node < n) {
            unsigned int hv = *(const unsigned int*)(c.Hs + (size_t)node * 64 + s * 4);
            float2v h0 = up8lo(hv), h1 = up8hi(hv);
            float4 bb = *(const float4*)(bias + s * 4);
            float d = c.dinv[node];
            v.x = fmaxf(bb.x + d * (acc[0].x + h0.x), 0.0f);
            v.y = fmaxf(bb.y + d * (acc[0].y + h0.y), 0.0f);
            v.z = fmaxf(bb.z + d * (acc[1].x + h1.x), 0.0f);
            v.w = fmaxf(bb.w + d * (acc[1].y + h1.y), 0.0f);
        }
        *(float4*)(&red[(wave * 2 + h) * 64 + s * 4]) = v;
    }
    __syncthreads();
    if (threadIdx.x < 64) {
        float acc8 = 0.0f;
#pragma unroll
        for (int r = 0; r < 8; ++r) acc8 += red[r * 64 + threadIdx.x];
        c.P[(size_t)b * 64 + threadIdx.x] = acc8;
    }
}

// colsum -> per-block partials in P2 (no atomics, no zero pass)
__global__ void k_colsum(Ctx c0, Ctx c1, int nb0, int rows) {
    int b = blockIdx.x; Ctx c = c0;
    if (b >= nb0) { c = c1; b -= nb0; }
    int f = threadIdx.x;  // 64
    float acc = 0.0f;
    for (int r = b; r < rows; r += nb0) acc += c.P[(size_t)r * 64 + f];
    c.P2[b * 64 + f] = acc;
}

// single-wave FC: reduce 256 partial rows, then out = fcb + (S/n) @ fcw^T
__global__ void k_fc(Ctx c0, Ctx c1, const float* __restrict__ fcw,
                     const float* __restrict__ fcb, int n) {
    Ctx c = blockIdx.x ? c1 : c0;
    __shared__ float S[64];
    int j = threadIdx.x;  // 64
    float s = 0.0f;
    for (int r = 0; r < 256; ++r) s += c.P2[r * 64 + j];
    S[j] = s;
    __syncthreads();
    float inv = 1.0f / (float)n;
    float acc = fcb[j];
#pragma unroll
    for (int k = 0; k < 64; ++k) acc += (S[k] * inv) * fcw[j * 64 + k];
    c.outp[j] = acc;
}

extern "C" void kernel_launch(void* const* d_in, const int* in_sizes, int n_in,
                              void* d_out, int out_size, void* d_ws, size_t ws_size,
                              hipStream_t stream) {
    const float* x[2]  = {(const float*)d_in[0], (const float*)d_in[1]};
    const int*   ei[2] = {(const int*)d_in[2], (const int*)d_in[3]};
    const float* W1  = (const float*)d_in[4];
    const float* b1  = (const float*)d_in[5];
    const float* W2  = (const float*)d_in[6];
    const float* b2  = (const float*)d_in[7];
    const float* fcw = (const float*)d_in[8];
    const float* fcb = (const float*)d_in[9];
    float* out = (float*)d_out;

    const int N  = in_sizes[0] / 64;
    const int E  = in_sizes[2] / 2;
    const int NF = N * 64;
    const int K  = (N + CHUNK - 1) / CHUNK;     // 782 buckets
    const int gGm = (N + 7) / 8;                // aggregate blocks (8 nodes each)
    const int nTiles = (N + 15) / 16;
    const int gMf = (nTiles + 3) / 4;
    const int gBin = (E + EPB - 1) / EPB;
    const int gK  = (K + TPB - 1) / TPB;

    auto al = [](size_t x) { return (x + 127) & ~(size_t)127; };
    size_t tempB = (size_t)K * CAP * 4;
    size_t abB   = ((size_t)NF + 64) * 2;
    size_t szRegion = al(tempB > abB ? tempB : abB);   // Ab aliases temp
    size_t szHs  = al((size_t)NF + 64);                // fp8: 1 B/elem
    size_t szCsr = al((size_t)E * 4);
    size_t szRp  = al((size_t)(N + 1) * 4);
    size_t szDi  = al((size_t)N * 4);
    size_t szCu  = al((size_t)K * CPAD * 4);           // padded cursors
    size_t szBB  = al((size_t)K * 4);
    size_t szP   = al((size_t)gGm * 64 * 4);
    size_t szP2  = al((size_t)256 * 64 * 4);
    size_t setB  = szRegion + szHs + szCsr + szRp + szDi + szCu + szBB + szP + szP2;
    size_t wtB   = 2 * al(64 * 64 * 2);
    bool batched = ws_size >= wtB + 2 * setB;

    char* base = (char*)d_ws;
    unsigned short* Wt1 = (unsigned short*)base;
    unsigned short* Wt2 = (unsigned short*)(base + al(64 * 64 * 2));

    auto mkctx = [&](int g, char* p) {
        Ctx c;
        c.X = x[g]; c.esrc = ei[g]; c.edst = ei[g] + E;
        c.temp = (unsigned int*)p; c.Ab = (unsigned short*)p; p += szRegion;
        c.Hs = (unsigned char*)p; p += szHs;
        c.csr = (int*)p; p += szCsr;
        c.row_ptr = (int*)p; p += szRp;
        c.dinv = (float*)p; p += szDi;
        c.cursorG = (int*)p; p += szCu;
        c.bucketBase = (int*)p; p += szBB;
        c.P = (float*)p; p += szP;
        c.P2 = (float*)p;
        c.outp = out + g * 64;
        return c;
    };
    char* set0 = base + wtB;
    Ctx c0 = mkctx(0, set0);
    Ctx c1 = mkctx(1, batched ? set0 + setB : set0);   // fallback: shares set0

    k_prepW2<<<2, 256, 0, stream>>>(W1, W2, Wt1, Wt2);

    auto pipe = [&](Ctx A, Ctx B, int mult) {
        k_zeroCur<<<mult * gK, TPB, 0, stream>>>(A, B, gK, K);
        k_binA<<<mult * gBin, 256, 0, stream>>>(A, B, gBin, E, K);
        k_scanK<<<mult, 1024, 0, stream>>>(A, B, K, N, E);
        k_csrb<<<mult * K, 256, 0, stream>>>(A, B, K, N);
        k_gemm1<<<mult * gMf, 256, 0, stream>>>(A, B, gMf, Wt1, nTiles, N);
        k_agg1<<<mult * gGm, 256, 0, stream>>>(A, B, gGm, b1, N);
        k_gemm2<<<mult * gMf, 256, 0, stream>>>(A, B, gMf, Wt2, nTiles, N);
        k_agg2<<<mult * gGm, 256, 0, stream>>>(A, B, gGm, b2, N);
        k_colsum<<<mult * 256, 64, 0, stream>>>(A, B, 256, gGm);
        k_fc<<<mult, 64, 0, stream>>>(A, B, fcw, fcb, N);
    };

    if (batched) {
        pipe(c0, c1, 2);
    } else {
        pipe(c0, c0, 1);   // sequential, shared buffer set
        pipe(c1, c1, 1);
    }
}

// Round 17
// 321.704 us; speedup vs baseline: 1.3576x; 1.0710x over previous
//
#include <hip/hip_runtime.h>

// SiameseGNN round 17: binA at 1024 threads/block (occupancy fix).
//
// R16 evidence: binA 60-70us, LDS 60KB -> 2 blocks x 4 waves = 8 waves/CU
// (Occupancy 12%), VALU 3.8%, HBM 8% -- the LDS counting sort fixed write
// amplification (WRITE 84->29MB, burst theory validated) but starved the CU
// of latency-hiding waves. Fix: same algorithm, 1024-thread blocks -- same
// 60KB LDS but 16 waves/block resident, 4x shorter per-wave serial phases;
// scan becomes 1 elem/thread. Everything else unchanged from R16
// (8-deep gather bursts, fp8 rows, LDS-sort, batching).

#define TPB    256
#define CHUNK  128
#define SHIFT  7
#define KMAX   1024
#define CAP    2560
#define EPB    8192
#define CPAD   16      // cursorG stride (ints)

typedef __attribute__((ext_vector_type(8))) short short8;
typedef __attribute__((ext_vector_type(4))) float f32x4;
typedef __attribute__((ext_vector_type(2))) float float2v;

struct Ctx {
    const float* X; const int* esrc; const int* edst;
    unsigned int* temp; unsigned short* Ab; unsigned char* Hs;
    int* csr; int* row_ptr; float* dinv; int* cursorG; int* bucketBase;
    float* P; float* P2; float* outp;
};

__device__ __forceinline__ unsigned short f2bf(float x) {
    union { float f; unsigned int i; } c; c.f = x;
    unsigned int r = c.i + 0x7FFFu + ((c.i >> 16) & 1u);   // RNE
    return (unsigned short)(r >> 16);
}
__device__ __forceinline__ unsigned char f2fp8(float x) {
    int p = __builtin_amdgcn_cvt_pk_fp8_f32(x, x, 0, false);
    return (unsigned char)(p & 0xFF);
}
__device__ __forceinline__ float2v up8lo(unsigned int w) {
    return __builtin_amdgcn_cvt_pk_f32_fp8(w, false);
}
__device__ __forceinline__ float2v up8hi(unsigned int w) {
    return __builtin_amdgcn_cvt_pk_f32_fp8(w, true);
}

__global__ void k_prepW2(const float* __restrict__ W1, const float* __restrict__ W2,
                         unsigned short* __restrict__ Wt1, unsigned short* __restrict__ Wt2) {
    const float* W = blockIdx.x ? W2 : W1;
    unsigned short* Wt = blockIdx.x ? Wt2 : Wt1;
    for (int i = threadIdx.x; i < 64 * 64; i += 256) {
        int n = i >> 6, k = i & 63;
        Wt[i] = f2bf(W[k * 64 + n]);
    }
}

__global__ void k_zeroCur(Ctx c0, Ctx c1, int nb0, int K) {
    int b = blockIdx.x; Ctx c = c0;
    if (b >= nb0) { c = c1; b -= nb0; }
    int i = b * blockDim.x + threadIdx.x;
    if (i < K) c.cursorG[i * CPAD] = 0;
}

// binA: LDS counting sort per block, burst segment writes. 1024 threads:
// 16 waves/block resident on one CU (was 4) -- same 60KB LDS.
__global__ __launch_bounds__(1024) void k_binA(Ctx c0, Ctx c1, int nb0, int E, int K) {
    __shared__ int cnt[KMAX];
    __shared__ int ofs[KMAX];
    __shared__ int segBase[KMAX];
    __shared__ unsigned int sorted[EPB];
    __shared__ unsigned short bkt[EPB];
    int b = blockIdx.x; Ctx c = c0;
    if (b >= nb0) { c = c1; b -= nb0; }
    int tid = threadIdx.x;               // 0..1023 == KMAX
    cnt[tid] = 0;
    __syncthreads();
    int base = b * EPB;
    int tot = E - base; if (tot > EPB) tot = EPB;
    // pass 1: count
#pragma unroll
    for (int k = 0; k < EPB / 1024; ++k) {
        int e = base + k * 1024 + tid;
        if (e < E) atomicAdd(&cnt[c.edst[e] >> SHIFT], 1);
    }
    __syncthreads();
    // 1024-wide inclusive scan (1 elem/thread) -> exclusive ofs
    int v = cnt[tid];
    segBase[tid] = v;
    __syncthreads();
#pragma unroll
    for (int off = 1; off < 1024; off <<= 1) {
        int t = (tid >= off) ? segBase[tid - off] : 0;
        __syncthreads();
        segBase[tid] += t;
        __syncthreads();
    }
    ofs[tid] = segBase[tid] - v;
    __syncthreads();
    // reserve global segments; reset cnt as scatter cursor
    if (tid < K) {
        segBase[tid] = v ? atomicAdd(&c.cursorG[tid * CPAD], v) : 0;
    } else {
        segBase[tid] = 0;
    }
    cnt[tid] = 0;
    __syncthreads();
    // pass 2: scatter into LDS sorted order (edges re-read, L2-hot)
#pragma unroll
    for (int k = 0; k < EPB / 1024; ++k) {
        int e = base + k * 1024 + tid;
        if (e < E) {
            int d = c.edst[e];
            int bk = d >> SHIFT;
            int r = atomicAdd(&cnt[bk], 1);
            int p = ofs[bk] + r;
            sorted[p] = ((unsigned int)(d & (CHUNK - 1)) << 17) | (unsigned int)c.esrc[e];
            bkt[p] = (unsigned short)bk;
        }
    }
    __syncthreads();
    // output: consecutive p -> contiguous run per bucket -> lines filled hot
    for (int p = tid; p < tot; p += 1024) {
        unsigned int vv = sorted[p];
        int bk = bkt[p];
        int pos = segBase[bk] + (p - ofs[bk]);
        if (pos < CAP) c.temp[(size_t)bk * CAP + pos] = vv;
    }
}

__global__ __launch_bounds__(1024) void k_scanK(Ctx c0, Ctx c1, int K, int N, int E) {
    Ctx c = blockIdx.x ? c1 : c0;
    __shared__ int s[1024];
    int tid = threadIdx.x;
    int v = (tid < K) ? c.cursorG[tid * CPAD] : 0;
    s[tid] = v;
    __syncthreads();
#pragma unroll
    for (int off = 1; off < 1024; off <<= 1) {
        int t = (tid >= off) ? s[tid - off] : 0;
        __syncthreads();
        s[tid] += t;
        __syncthreads();
    }
    if (tid < K) c.bucketBase[tid] = s[tid] - v;
    if (tid == 0) c.row_ptr[N] = E;
}

// Per-bucket LDS counting sort -> contiguous csr slice + row_ptr + dinv.
__global__ __launch_bounds__(256) void k_csrb(Ctx c0, Ctx c1, int nb0, int N) {
    __shared__ int deg[CHUNK];
    __shared__ int lofs[CHUNK];
    __shared__ int cur[CHUNK];
    int b = blockIdx.x; Ctx c = c0;
    if (b >= nb0) { c = c1; b -= nb0; }
    int tid = threadIdx.x;
    if (tid < CHUNK) deg[tid] = 0;
    __syncthreads();
    int cnt = c.cursorG[b * CPAD]; if (cnt > CAP) cnt = CAP;
    const size_t tb = (size_t)b * CAP;
    for (int i = tid; i < cnt; i += 256) atomicAdd(&deg[c.temp[tb + i] >> 17], 1);
    __syncthreads();
    if (tid < CHUNK) lofs[tid] = deg[tid];
    __syncthreads();
#pragma unroll
    for (int off = 1; off < CHUNK; off <<= 1) {
        int t = (tid < CHUNK && tid >= off) ? lofs[tid - off] : 0;
        __syncthreads();
        if (tid < CHUNK) lofs[tid] += t;
        __syncthreads();
    }
    int base = c.bucketBase[b];
    if (tid < CHUNK) {
        int excl = lofs[tid] - deg[tid];
        lofs[tid] = excl;
        cur[tid] = 0;
        int node = b * CHUNK + tid;
        if (node < N) {
            c.row_ptr[node] = base + excl;
            c.dinv[node] = rsqrtf((float)deg[tid] + 1.0f);
        }
    }
    __syncthreads();
    for (int i = tid; i < cnt; i += 256) {
        unsigned int p = c.temp[tb + i];
        int dl = p >> 17;
        int rank = atomicAdd(&cur[dl], 1);
        c.csr[base + lofs[dl] + rank] = (int)(p & 0x1FFFFu);
    }
}

// Shared MFMA body: A-fragments provided; B from Wt; store fp8 Hs.
__device__ __forceinline__ void mfma_tail(short8 a0, short8 a1,
                                          const unsigned short* __restrict__ Wt,
                                          unsigned char* __restrict__ Hs,
                                          int row0, int r, int q, int N) {
    short8 bfrag[4][2];
#pragma unroll
    for (int ct = 0; ct < 4; ++ct)
#pragma unroll
        for (int kb = 0; kb < 2; ++kb)
            bfrag[ct][kb] = *(const short8*)(Wt + (ct * 16 + r) * 64 + q * 8 + 32 * kb);
    f32x4 acc[4];
#pragma unroll
    for (int ct = 0; ct < 4; ++ct) {
        acc[ct] = (f32x4){0.0f, 0.0f, 0.0f, 0.0f};
        acc[ct] = __builtin_amdgcn_mfma_f32_16x16x32_bf16(a0, bfrag[ct][0], acc[ct], 0, 0, 0);
        acc[ct] = __builtin_amdgcn_mfma_f32_16x16x32_bf16(a1, bfrag[ct][1], acc[ct], 0, 0, 0);
    }
#pragma unroll
    for (int reg = 0; reg < 4; ++reg) {
        int row = row0 + q * 4 + reg;
        if (row < N) {
            size_t base = (size_t)row * 64 + r;
#pragma unroll
            for (int ct = 0; ct < 4; ++ct)
                Hs[base + ct * 16] = f2fp8(acc[ct][reg]);
        }
    }
}

// GEMM1: fp32 X in, dinv folded into A-fragment conversion.
__global__ __launch_bounds__(256) void k_gemm1(Ctx c0, Ctx c1, int nb0,
                                               const unsigned short* __restrict__ Wt,
                                               int nTiles, int N) {
    int b = blockIdx.x; Ctx c = c0;
    if (b >= nb0) { c = c1; b -= nb0; }
    int wave = threadIdx.x >> 6, lane = threadIdx.x & 63;
    int tile = b * 4 + wave;
    if (tile >= nTiles) return;
    int r = lane & 15, q = lane >> 4;
    int row0 = tile * 16;
    int row = row0 + r;
    int rr = row < N ? row : N - 1;
    float d = c.dinv[rr];
    const float* xrow = c.X + (size_t)rr * 64 + q * 8;
    short8 a0, a1;
#pragma unroll
    for (int j = 0; j < 8; ++j) a0[j] = (short)f2bf(xrow[j] * d);
#pragma unroll
    for (int j = 0; j < 8; ++j) a1[j] = (short)f2bf(xrow[32 + j] * d);
    mfma_tail(a0, a1, Wt, c.Hs, row0, r, q, N);
}

// GEMM2: bf16 Ab in (already dinv-scaled by aggregate1).
__global__ __launch_bounds__(256) void k_gemm2(Ctx c0, Ctx c1, int nb0,
                                               const unsigned short* __restrict__ Wt,
                                               int nTiles, int N) {
    int b = blockIdx.x; Ctx c = c0;
    if (b >= nb0) { c = c1; b -= nb0; }
    int wave = threadIdx.x >> 6, lane = threadIdx.x & 63;
    int tile = b * 4 + wave;
    if (tile >= nTiles) return;
    int r = lane & 15, q = lane >> 4;
    int row0 = tile * 16;
    const unsigned short* xrow = c.Ab + (size_t)(row0 + r) * 64 + q * 8;
    short8 a0 = *(const short8*)(xrow);
    short8 a1 = *(const short8*)(xrow + 32);
    mfma_tail(a0, a1, Wt, c.Hs, row0, r, q, N);
}

// 2 nodes per wave; per half: 2 groups x 16 lanes, lane s covers fp8
// channels 4s..4s+3. 16-edge bursts: 8 unconditional gathers (invalid
// slots -> row 0, L1-hot) then 8 masked consumes -- vmcnt depth 8.
__device__ __forceinline__ void agg_node2(const unsigned char* __restrict__ Hs,
                                          const int* __restrict__ csr,
                                          int beg, int deg, int maxd, int lane,
                                          float2v* acc) {
    int hbase = lane & 32;
    int hl = lane & 31;
    int g = (lane >> 4) & 1;
    int s = lane & 15;
    for (int base = 0; base < maxd; base += 32) {
        int idx = (base + hl < deg) ? csr[beg + base + hl] : 0;   // coalesced/half
        int mW = maxd - base; if (mW > 32) mW = 32;               // wave-uniform
        for (int t = 0; t < mW; t += 16) {                        // 16-edge burst
            unsigned int h[8];
            bool valid[8];
#pragma unroll
            for (int u = 0; u < 8; ++u) {                         // issue phase
                int slot = t + 2 * u + g;                         // <= 31
                int su = __shfl(idx, hbase + slot, 64);           // exec-uniform
                h[u] = *(const unsigned int*)(Hs + (size_t)su * 64 + s * 4);
                valid[u] = (base + slot < deg);
            }
#pragma unroll
            for (int u = 0; u < 8; ++u) {                         // consume phase
                unsigned int w = valid[u] ? h[u] : 0u;            // cndmask; fp8 0 = +0.0
                acc[0] += up8lo(w); acc[1] += up8hi(w);
            }
        }
    }
    // merge the half's 2 groups (bit 4); does not cross halves
#pragma unroll
    for (int k = 0; k < 2; ++k) {
        float2v o;
        o.x = __shfl_xor(acc[k].x, 16, 64); o.y = __shfl_xor(acc[k].y, 16, 64);
        acc[k] += o;
    }
}

// layer-1: Ab[d, f] = bf16( dinv[d] * relu(b[f] + dinv[d] * agg) )
__global__ __launch_bounds__(256) void k_agg1(Ctx c0, Ctx c1, int nb0,
                                              const float* __restrict__ bias, int n) {
    int b = blockIdx.x; Ctx c = c0;
    if (b >= nb0) { c = c1; b -= nb0; }
    int wave = threadIdx.x >> 6, lane = threadIdx.x & 63;
    int h = lane >> 5;
    int node = b * 8 + wave * 2 + h;
    int nd = node < n ? node : 0;
    int beg = c.row_ptr[nd];
    int deg = (node < n) ? (c.row_ptr[nd + 1] - beg) : 0;
    int od = __shfl_xor(deg, 32, 64);
    int maxd = deg > od ? deg : od;      // wave-uniform
    float2v acc[2] = {{0.f, 0.f}, {0.f, 0.f}};
    agg_node2(c.Hs, c.csr, beg, deg, maxd, lane, acc);
    if (((lane >> 4) & 1) == 0 && node < n) {
        int s = lane & 15;
        unsigned int hv = *(const unsigned int*)(c.Hs + (size_t)node * 64 + s * 4);
        float2v h0 = up8lo(hv), h1 = up8hi(hv);
        float4 bb = *(const float4*)(bias + s * 4);
        float d = c.dinv[node];
        float v0 = fmaxf(bb.x + d * (acc[0].x + h0.x), 0.0f) * d;
        float v1 = fmaxf(bb.y + d * (acc[0].y + h0.y), 0.0f) * d;
        float v2 = fmaxf(bb.z + d * (acc[1].x + h1.x), 0.0f) * d;
        float v3 = fmaxf(bb.w + d * (acc[1].y + h1.y), 0.0f) * d;
        ushort4 o;
        o.x = f2bf(v0); o.y = f2bf(v1); o.z = f2bf(v2); o.w = f2bf(v3);
        *(ushort4*)(c.Ab + (size_t)node * 64 + s * 4) = o;
    }
}

// layer-2: block-reduce 8 relu'd rows -> P[block, f]
__global__ __launch_bounds__(256) void k_agg2(Ctx c0, Ctx c1, int nb0,
                                              const float* __restrict__ bias, int n) {
    __shared__ float red[8 * 64];
    int b = blockIdx.x; Ctx c = c0;
    if (b >= nb0) { c = c1; b -= nb0; }
    int wave = threadIdx.x >> 6, lane = threadIdx.x & 63;
    int h = lane >> 5;
    int node = b * 8 + wave * 2 + h;
    int nd = node < n ? node : 0;
    int beg = c.row_ptr[nd];
    int deg = (node < n) ? (c.row_ptr[nd + 1] - beg) : 0;
    int od = __shfl_xor(deg, 32, 64);
    int maxd = deg > od ? deg : od;
    float2v acc[2] = {{0.f, 0.f}, {0.f, 0.f}};
    agg_node2(c.Hs, c.csr, beg, deg, maxd, lane, acc);
    if (((lane >> 4) & 1) == 0) {
        int s = lane & 15;
        float4 v = {0.f, 0.f, 0.f, 0.f};
        if (node < n) {
            unsigned int hv = *(const unsigned int*)(c.Hs + (size_t)node * 64 + s * 4);
            float2v h0 = up8lo(hv), h1 = up8hi(hv);
            float4 bb = *(const float4*)(bias + s * 4);
            float d = c.dinv[node];
            v.x = fmaxf(bb.x + d * (acc[0].x + h0.x), 0.0f);
            v.y = fmaxf(bb.y + d * (acc[0].y + h0.y), 0.0f);
            v.z = fmaxf(bb.z + d * (acc[1].x + h1.x), 0.0f);
            v.w = fmaxf(bb.w + d * (acc[1].y + h1.y), 0.0f);
        }
        *(float4*)(&red[(wave * 2 + h) * 64 + s * 4]) = v;
    }
    __syncthreads();
    if (threadIdx.x < 64) {
        float acc8 = 0.0f;
#pragma unroll
        for (int r = 0; r < 8; ++r) acc8 += red[r * 64 + threadIdx.x];
        c.P[(size_t)b * 64 + threadIdx.x] = acc8;
    }
}

// colsum -> per-block partials in P2 (no atomics, no zero pass)
__global__ void k_colsum(Ctx c0, Ctx c1, int nb0, int rows) {
    int b = blockIdx.x; Ctx c = c0;
    if (b >= nb0) { c = c1; b -= nb0; }
    int f = threadIdx.x;  // 64
    float acc = 0.0f;
    for (int r = b; r < rows; r += nb0) acc += c.P[(size_t)r * 64 + f];
    c.P2[b * 64 + f] = acc;
}

// single-wave FC: reduce 256 partial rows, then out = fcb + (S/n) @ fcw^T
__global__ void k_fc(Ctx c0, Ctx c1, const float* __restrict__ fcw,
                     const float* __restrict__ fcb, int n) {
    Ctx c = blockIdx.x ? c1 : c0;
    __shared__ float S[64];
    int j = threadIdx.x;  // 64
    float s = 0.0f;
    for (int r = 0; r < 256; ++r) s += c.P2[r * 64 + j];
    S[j] = s;
    __syncthreads();
    float inv = 1.0f / (float)n;
    float acc = fcb[j];
#pragma unroll
    for (int k = 0; k < 64; ++k) acc += (S[k] * inv) * fcw[j * 64 + k];
    c.outp[j] = acc;
}

extern "C" void kernel_launch(void* const* d_in, const int* in_sizes, int n_in,
                              void* d_out, int out_size, void* d_ws, size_t ws_size,
                              hipStream_t stream) {
    const float* x[2]  = {(const float*)d_in[0], (const float*)d_in[1]};
    const int*   ei[2] = {(const int*)d_in[2], (const int*)d_in[3]};
    const float* W1  = (const float*)d_in[4];
    const float* b1  = (const float*)d_in[5];
    const float* W2  = (const float*)d_in[6];
    const float* b2  = (const float*)d_in[7];
    const float* fcw = (const float*)d_in[8];
    const float* fcb = (const float*)d_in[9];
    float* out = (float*)d_out;

    const int N  = in_sizes[0] / 64;
    const int E  = in_sizes[2] / 2;
    const int NF = N * 64;
    const int K  = (N + CHUNK - 1) / CHUNK;     // 782 buckets
    const int gGm = (N + 7) / 8;                // aggregate blocks (8 nodes each)
    const int nTiles = (N + 15) / 16;
    const int gMf = (nTiles + 3) / 4;
    const int gBin = (E + EPB - 1) / EPB;
    const int gK  = (K + TPB - 1) / TPB;

    auto al = [](size_t x) { return (x + 127) & ~(size_t)127; };
    size_t tempB = (size_t)K * CAP * 4;
    size_t abB   = ((size_t)NF + 64) * 2;
    size_t szRegion = al(tempB > abB ? tempB : abB);   // Ab aliases temp
    size_t szHs  = al((size_t)NF + 64);                // fp8: 1 B/elem
    size_t szCsr = al((size_t)E * 4);
    size_t szRp  = al((size_t)(N + 1) * 4);
    size_t szDi  = al((size_t)N * 4);
    size_t szCu  = al((size_t)K * CPAD * 4);           // padded cursors
    size_t szBB  = al((size_t)K * 4);
    size_t szP   = al((size_t)gGm * 64 * 4);
    size_t szP2  = al((size_t)256 * 64 * 4);
    size_t setB  = szRegion + szHs + szCsr + szRp + szDi + szCu + szBB + szP + szP2;
    size_t wtB   = 2 * al(64 * 64 * 2);
    bool batched = ws_size >= wtB + 2 * setB;

    char* base = (char*)d_ws;
    unsigned short* Wt1 = (unsigned short*)base;
    unsigned short* Wt2 = (unsigned short*)(base + al(64 * 64 * 2));

    auto mkctx = [&](int g, char* p) {
        Ctx c;
        c.X = x[g]; c.esrc = ei[g]; c.edst = ei[g] + E;
        c.temp = (unsigned int*)p; c.Ab = (unsigned short*)p; p += szRegion;
        c.Hs = (unsigned char*)p; p += szHs;
        c.csr = (int*)p; p += szCsr;
        c.row_ptr = (int*)p; p += szRp;
        c.dinv = (float*)p; p += szDi;
        c.cursorG = (int*)p; p += szCu;
        c.bucketBase = (int*)p; p += szBB;
        c.P = (float*)p; p += szP;
        c.P2 = (float*)p;
        c.outp = out + g * 64;
        return c;
    };
    char* set0 = base + wtB;
    Ctx c0 = mkctx(0, set0);
    Ctx c1 = mkctx(1, batched ? set0 + setB : set0);   // fallback: shares set0

    k_prepW2<<<2, 256, 0, stream>>>(W1, W2, Wt1, Wt2);

    auto pipe = [&](Ctx A, Ctx B, int mult) {
        k_zeroCur<<<mult * gK, TPB, 0, stream>>>(A, B, gK, K);
        k_binA<<<mult * gBin, 1024, 0, stream>>>(A, B, gBin, E, K);
        k_scanK<<<mult, 1024, 0, stream>>>(A, B, K, N, E);
        k_csrb<<<mult * K, 256, 0, stream>>>(A, B, K, N);
        k_gemm1<<<mult * gMf, 256, 0, stream>>>(A, B, gMf, Wt1, nTiles, N);
        k_agg1<<<mult * gGm, 256, 0, stream>>>(A, B, gGm, b1, N);
        k_gemm2<<<mult * gMf, 256, 0, stream>>>(A, B, gMf, Wt2, nTiles, N);
        k_agg2<<<mult * gGm, 256, 0, stream>>>(A, B, gGm, b2, N);
        k_colsum<<<mult * 256, 64, 0, stream>>>(A, B, 256, gGm);
        k_fc<<<mult, 64, 0, stream>>>(A, B, fcw, fcb, N);
    };

    if (batched) {
        pipe(c0, c1, 2);
    } else {
        pipe(c0, c0, 1);   // sequential, shared buffer set
        pipe(c1, c1, 1);
    }
}

// Round 18
// 320.769 us; speedup vs baseline: 1.3616x; 1.0029x over previous
//
#include <hip/hip_runtime.h>

// SiameseGNN round 18: sentinel-row aggregate (no masking VALU) + XCD-
// partitioned gather blocks.
//
// R17 evidence: k_agg1 54us, VALUBusy 79%, TCC 2.6 TB/s, FETCH 112MB of
// 205MB logical (both graphs' 6.4MB Hs fight for 4MiB/XCD L2).
//   fix 1: Hs row N = zeros (fp8 0x00); invalid edge slots load index N
//          at the csr read -> every gather accumulates unconditionally.
//          Removes 8 cmp + 8 cndmask per 16-edge burst.
//   fix 2: agg block mapping graph=(blockIdx>>2)&1 -- under round-robin
//          block->XCD dispatch, XCDs 0-3 own graph0, 4-7 own graph1:
//          halves per-XCD gather working set. Guarded heuristic
//          (linear fallback); validation signal = FETCH_SIZE drop.
// Everything else unchanged from R17.

#define TPB    256
#define CHUNK  128
#define SHIFT  7
#define KMAX   1024
#define CAP    2560
#define EPB    8192
#define CPAD   16      // cursorG stride (ints)

typedef __attribute__((ext_vector_type(8))) short short8;
typedef __attribute__((ext_vector_type(4))) float f32x4;
typedef __attribute__((ext_vector_type(2))) float float2v;

struct Ctx {
    const float* X; const int* esrc; const int* edst;
    unsigned int* temp; unsigned short* Ab; unsigned char* Hs;
    int* csr; int* row_ptr; float* dinv; int* cursorG; int* bucketBase;
    float* P; float* P2; float* outp;
};

__device__ __forceinline__ unsigned short f2bf(float x) {
    union { float f; unsigned int i; } c; c.f = x;
    unsigned int r = c.i + 0x7FFFu + ((c.i >> 16) & 1u);   // RNE
    return (unsigned short)(r >> 16);
}
__device__ __forceinline__ unsigned char f2fp8(float x) {
    int p = __builtin_amdgcn_cvt_pk_fp8_f32(x, x, 0, false);
    return (unsigned char)(p & 0xFF);
}
__device__ __forceinline__ float2v up8lo(unsigned int w) {
    return __builtin_amdgcn_cvt_pk_f32_fp8(w, false);
}
__device__ __forceinline__ float2v up8hi(unsigned int w) {
    return __builtin_amdgcn_cvt_pk_f32_fp8(w, true);
}

__global__ void k_prepW2(const float* __restrict__ W1, const float* __restrict__ W2,
                         unsigned short* __restrict__ Wt1, unsigned short* __restrict__ Wt2) {
    const float* W = blockIdx.x ? W2 : W1;
    unsigned short* Wt = blockIdx.x ? Wt2 : Wt1;
    for (int i = threadIdx.x; i < 64 * 64; i += 256) {
        int n = i >> 6, k = i & 63;
        Wt[i] = f2bf(W[k * 64 + n]);
    }
}

// zero cursors + zero the Hs sentinel row (row N; ws is re-poisoned per call)
__global__ void k_zeroCur(Ctx c0, Ctx c1, int nb0, int K, int N) {
    int b = blockIdx.x; Ctx c = c0;
    if (b >= nb0) { c = c1; b -= nb0; }
    int i = b * blockDim.x + threadIdx.x;
    if (i < K) c.cursorG[i * CPAD] = 0;
    if (b == 0 && threadIdx.x < 64) c.Hs[(size_t)N * 64 + threadIdx.x] = 0;
}

// binA: LDS counting sort per block, burst segment writes. 1024 threads.
__global__ __launch_bounds__(1024) void k_binA(Ctx c0, Ctx c1, int nb0, int E, int K) {
    __shared__ int cnt[KMAX];
    __shared__ int ofs[KMAX];
    __shared__ int segBase[KMAX];
    __shared__ unsigned int sorted[EPB];
    __shared__ unsigned short bkt[EPB];
    int b = blockIdx.x; Ctx c = c0;
    if (b >= nb0) { c = c1; b -= nb0; }
    int tid = threadIdx.x;               // 0..1023 == KMAX
    cnt[tid] = 0;
    __syncthreads();
    int base = b * EPB;
    int tot = E - base; if (tot > EPB) tot = EPB;
#pragma unroll
    for (int k = 0; k < EPB / 1024; ++k) {
        int e = base + k * 1024 + tid;
        if (e < E) atomicAdd(&cnt[c.edst[e] >> SHIFT], 1);
    }
    __syncthreads();
    int v = cnt[tid];
    segBase[tid] = v;
    __syncthreads();
#pragma unroll
    for (int off = 1; off < 1024; off <<= 1) {
        int t = (tid >= off) ? segBase[tid - off] : 0;
        __syncthreads();
        segBase[tid] += t;
        __syncthreads();
    }
    ofs[tid] = segBase[tid] - v;
    __syncthreads();
    if (tid < K) {
        segBase[tid] = v ? atomicAdd(&c.cursorG[tid * CPAD], v) : 0;
    } else {
        segBase[tid] = 0;
    }
    cnt[tid] = 0;
    __syncthreads();
#pragma unroll
    for (int k = 0; k < EPB / 1024; ++k) {
        int e = base + k * 1024 + tid;
        if (e < E) {
            int d = c.edst[e];
            int bk = d >> SHIFT;
            int r = atomicAdd(&cnt[bk], 1);
            int p = ofs[bk] + r;
            sorted[p] = ((unsigned int)(d & (CHUNK - 1)) << 17) | (unsigned int)c.esrc[e];
            bkt[p] = (unsigned short)bk;
        }
    }
    __syncthreads();
    for (int p = tid; p < tot; p += 1024) {
        unsigned int vv = sorted[p];
        int bk = bkt[p];
        int pos = segBase[bk] + (p - ofs[bk]);
        if (pos < CAP) c.temp[(size_t)bk * CAP + pos] = vv;
    }
}

__global__ __launch_bounds__(1024) void k_scanK(Ctx c0, Ctx c1, int K, int N, int E) {
    Ctx c = blockIdx.x ? c1 : c0;
    __shared__ int s[1024];
    int tid = threadIdx.x;
    int v = (tid < K) ? c.cursorG[tid * CPAD] : 0;
    s[tid] = v;
    __syncthreads();
#pragma unroll
    for (int off = 1; off < 1024; off <<= 1) {
        int t = (tid >= off) ? s[tid - off] : 0;
        __syncthreads();
        s[tid] += t;
        __syncthreads();
    }
    if (tid < K) c.bucketBase[tid] = s[tid] - v;
    if (tid == 0) c.row_ptr[N] = E;
}

// Per-bucket LDS counting sort -> contiguous csr slice + row_ptr + dinv.
__global__ __launch_bounds__(256) void k_csrb(Ctx c0, Ctx c1, int nb0, int N) {
    __shared__ int deg[CHUNK];
    __shared__ int lofs[CHUNK];
    __shared__ int cur[CHUNK];
    int b = blockIdx.x; Ctx c = c0;
    if (b >= nb0) { c = c1; b -= nb0; }
    int tid = threadIdx.x;
    if (tid < CHUNK) deg[tid] = 0;
    __syncthreads();
    int cnt = c.cursorG[b * CPAD]; if (cnt > CAP) cnt = CAP;
    const size_t tb = (size_t)b * CAP;
    for (int i = tid; i < cnt; i += 256) atomicAdd(&deg[c.temp[tb + i] >> 17], 1);
    __syncthreads();
    if (tid < CHUNK) lofs[tid] = deg[tid];
    __syncthreads();
#pragma unroll
    for (int off = 1; off < CHUNK; off <<= 1) {
        int t = (tid < CHUNK && tid >= off) ? lofs[tid - off] : 0;
        __syncthreads();
        if (tid < CHUNK) lofs[tid] += t;
        __syncthreads();
    }
    int base = c.bucketBase[b];
    if (tid < CHUNK) {
        int excl = lofs[tid] - deg[tid];
        lofs[tid] = excl;
        cur[tid] = 0;
        int node = b * CHUNK + tid;
        if (node < N) {
            c.row_ptr[node] = base + excl;
            c.dinv[node] = rsqrtf((float)deg[tid] + 1.0f);
        }
    }
    __syncthreads();
    for (int i = tid; i < cnt; i += 256) {
        unsigned int p = c.temp[tb + i];
        int dl = p >> 17;
        int rank = atomicAdd(&cur[dl], 1);
        c.csr[base + lofs[dl] + rank] = (int)(p & 0x1FFFFu);
    }
}

// Shared MFMA body: A-fragments provided; B from Wt; store fp8 Hs.
__device__ __forceinline__ void mfma_tail(short8 a0, short8 a1,
                                          const unsigned short* __restrict__ Wt,
                                          unsigned char* __restrict__ Hs,
                                          int row0, int r, int q, int N) {
    short8 bfrag[4][2];
#pragma unroll
    for (int ct = 0; ct < 4; ++ct)
#pragma unroll
        for (int kb = 0; kb < 2; ++kb)
            bfrag[ct][kb] = *(const short8*)(Wt + (ct * 16 + r) * 64 + q * 8 + 32 * kb);
    f32x4 acc[4];
#pragma unroll
    for (int ct = 0; ct < 4; ++ct) {
        acc[ct] = (f32x4){0.0f, 0.0f, 0.0f, 0.0f};
        acc[ct] = __builtin_amdgcn_mfma_f32_16x16x32_bf16(a0, bfrag[ct][0], acc[ct], 0, 0, 0);
        acc[ct] = __builtin_amdgcn_mfma_f32_16x16x32_bf16(a1, bfrag[ct][1], acc[ct], 0, 0, 0);
    }
#pragma unroll
    for (int reg = 0; reg < 4; ++reg) {
        int row = row0 + q * 4 + reg;
        if (row < N) {
            size_t base = (size_t)row * 64 + r;
#pragma unroll
            for (int ct = 0; ct < 4; ++ct)
                Hs[base + ct * 16] = f2fp8(acc[ct][reg]);
        }
    }
}

// GEMM1: fp32 X in, dinv folded into A-fragment conversion.
__global__ __launch_bounds__(256) void k_gemm1(Ctx c0, Ctx c1, int nb0,
                                               const unsigned short* __restrict__ Wt,
                                               int nTiles, int N) {
    int b = blockIdx.x; Ctx c = c0;
    if (b >= nb0) { c = c1; b -= nb0; }
    int wave = threadIdx.x >> 6, lane = threadIdx.x & 63;
    int tile = b * 4 + wave;
    if (tile >= nTiles) return;
    int r = lane & 15, q = lane >> 4;
    int row0 = tile * 16;
    int row = row0 + r;
    int rr = row < N ? row : N - 1;
    float d = c.dinv[rr];
    const float* xrow = c.X + (size_t)rr * 64 + q * 8;
    short8 a0, a1;
#pragma unroll
    for (int j = 0; j < 8; ++j) a0[j] = (short)f2bf(xrow[j] * d);
#pragma unroll
    for (int j = 0; j < 8; ++j) a1[j] = (short)f2bf(xrow[32 + j] * d);
    mfma_tail(a0, a1, Wt, c.Hs, row0, r, q, N);
}

// GEMM2: bf16 Ab in (already dinv-scaled by aggregate1).
__global__ __launch_bounds__(256) void k_gemm2(Ctx c0, Ctx c1, int nb0,
                                               const unsigned short* __restrict__ Wt,
                                               int nTiles, int N) {
    int b = blockIdx.x; Ctx c = c0;
    if (b >= nb0) { c = c1; b -= nb0; }
    int wave = threadIdx.x >> 6, lane = threadIdx.x & 63;
    int tile = b * 4 + wave;
    if (tile >= nTiles) return;
    int r = lane & 15, q = lane >> 4;
    int row0 = tile * 16;
    const unsigned short* xrow = c.Ab + (size_t)(row0 + r) * 64 + q * 8;
    short8 a0 = *(const short8*)(xrow);
    short8 a1 = *(const short8*)(xrow + 32);
    mfma_tail(a0, a1, Wt, c.Hs, row0, r, q, N);
}

// agg block mapping: XCD-partition swizzle (graph = (blockIdx>>2)&1) when
// swz, else linear split. Round-robin block->XCD heuristic: XCDs 0-3 get
// graph0, 4-7 get graph1 -> halves per-XCD gather working set.
__device__ __forceinline__ void agg_map(int bi, int nb0, int swz,
                                        const Ctx& c0, const Ctx& c1,
                                        Ctx& c, int& b) {
    if (swz) {
        int graph = (bi >> 2) & 1;
        b = ((bi >> 3) << 2) | (bi & 3);
        c = graph ? c1 : c0;
    } else {
        b = bi; c = c0;
        if (b >= nb0) { c = c1; b -= nb0; }
    }
}

// 2 nodes per wave; per half: 2 groups x 16 lanes, lane s covers fp8
// channels 4s..4s+3. 16-edge bursts, 8 unconditional gathers + 8
// unconditional consumes: invalid slots load sentinel row (all-zero fp8)
// via idx fallback at the csr read. No masking VALU at all.
__device__ __forceinline__ void agg_node2(const unsigned char* __restrict__ Hs,
                                          const int* __restrict__ csr,
                                          int beg, int deg, int maxd, int lane,
                                          int sent, float2v* acc) {
    int hbase = lane & 32;
    int hl = lane & 31;
    int g = (lane >> 4) & 1;
    int s = lane & 15;
    for (int base = 0; base < maxd; base += 32) {
        int idx = (base + hl < deg) ? csr[beg + base + hl] : sent;  // coalesced/half
        int mW = maxd - base; if (mW > 32) mW = 32;                 // wave-uniform
        for (int t = 0; t < mW; t += 16) {                          // 16-edge burst
            unsigned int h[8];
#pragma unroll
            for (int u = 0; u < 8; ++u) {                           // issue phase
                int slot = t + 2 * u + g;                           // <= 31
                int su = __shfl(idx, hbase + slot, 64);             // exec-uniform
                h[u] = *(const unsigned int*)(Hs + (size_t)su * 64 + s * 4);
            }
#pragma unroll
            for (int u = 0; u < 8; ++u) {                           // consume phase
                acc[0] += up8lo(h[u]); acc[1] += up8hi(h[u]);       // sentinel adds 0
            }
        }
    }
    // merge the half's 2 groups (bit 4); does not cross halves
#pragma unroll
    for (int k = 0; k < 2; ++k) {
        float2v o;
        o.x = __shfl_xor(acc[k].x, 16, 64); o.y = __shfl_xor(acc[k].y, 16, 64);
        acc[k] += o;
    }
}

// layer-1: Ab[d, f] = bf16( dinv[d] * relu(b[f] + dinv[d] * agg) )
__global__ __launch_bounds__(256) void k_agg1(Ctx c0, Ctx c1, int nb0, int swz,
                                              const float* __restrict__ bias, int n) {
    Ctx c; int b;
    agg_map(blockIdx.x, nb0, swz, c0, c1, c, b);
    int wave = threadIdx.x >> 6, lane = threadIdx.x & 63;
    int h = lane >> 5;
    int node = b * 8 + wave * 2 + h;
    int nd = node < n ? node : 0;
    int beg = c.row_ptr[nd];
    int deg = (node < n) ? (c.row_ptr[nd + 1] - beg) : 0;
    int od = __shfl_xor(deg, 32, 64);
    int maxd = deg > od ? deg : od;      // wave-uniform
    float2v acc[2] = {{0.f, 0.f}, {0.f, 0.f}};
    agg_node2(c.Hs, c.csr, beg, deg, maxd, lane, n, acc);
    if (((lane >> 4) & 1) == 0 && node < n) {
        int s = lane & 15;
        unsigned int hv = *(const unsigned int*)(c.Hs + (size_t)node * 64 + s * 4);
        float2v h0 = up8lo(hv), h1 = up8hi(hv);
        float4 bb = *(const float4*)(bias + s * 4);
        float d = c.dinv[node];
        float v0 = fmaxf(bb.x + d * (acc[0].x + h0.x), 0.0f) * d;
        float v1 = fmaxf(bb.y + d * (acc[0].y + h0.y), 0.0f) * d;
        float v2 = fmaxf(bb.z + d * (acc[1].x + h1.x), 0.0f) * d;
        float v3 = fmaxf(bb.w + d * (acc[1].y + h1.y), 0.0f) * d;
        ushort4 o;
        o.x = f2bf(v0); o.y = f2bf(v1); o.z = f2bf(v2); o.w = f2bf(v3);
        *(ushort4*)(c.Ab + (size_t)node * 64 + s * 4) = o;
    }
}

// layer-2: block-reduce 8 relu'd rows -> P[block, f]
__global__ __launch_bounds__(256) void k_agg2(Ctx c0, Ctx c1, int nb0, int swz,
                                              const float* __restrict__ bias, int n) {
    __shared__ float red[8 * 64];
    Ctx c; int b;
    agg_map(blockIdx.x, nb0, swz, c0, c1, c, b);
    int wave = threadIdx.x >> 6, lane = threadIdx.x & 63;
    int h = lane >> 5;
    int node = b * 8 + wave * 2 + h;
    int nd = node < n ? node : 0;
    int beg = c.row_ptr[nd];
    int deg = (node < n) ? (c.row_ptr[nd + 1] - beg) : 0;
    int od = __shfl_xor(deg, 32, 64);
    int maxd = deg > od ? deg : od;
    float2v acc[2] = {{0.f, 0.f}, {0.f, 0.f}};
    agg_node2(c.Hs, c.csr, beg, deg, maxd, lane, n, acc);
    if (((lane >> 4) & 1) == 0) {
        int s = lane & 15;
        float4 v = {0.f, 0.f, 0.f, 0.f};
        if (node < n) {
            unsigned int hv = *(const unsigned int*)(c.Hs + (size_t)node * 64 + s * 4);
            float2v h0 = up8lo(hv), h1 = up8hi(hv);
            float4 bb = *(const float4*)(bias + s * 4);
            float d = c.dinv[node];
            v.x = fmaxf(bb.x + d * (acc[0].x + h0.x), 0.0f);
            v.y = fmaxf(bb.y + d * (acc[0].y + h0.y), 0.0f);
            v.z = fmaxf(bb.z + d * (acc[1].x + h1.x), 0.0f);
            v.w = fmaxf(bb.w + d * (acc[1].y + h1.y), 0.0f);
        }
        *(float4*)(&red[(wave * 2 + h) * 64 + s * 4]) = v;
    }
    __syncthreads();
    if (threadIdx.x < 64) {
        float acc8 = 0.0f;
#pragma unroll
        for (int r = 0; r < 8; ++r) acc8 += red[r * 64 + threadIdx.x];
        c.P[(size_t)b * 64 + threadIdx.x] = acc8;
    }
}

// colsum -> per-block partials in P2 (no atomics, no zero pass)
__global__ void k_colsum(Ctx c0, Ctx c1, int nb0, int rows) {
    int b = blockIdx.x; Ctx c = c0;
    if (b >= nb0) { c = c1; b -= nb0; }
    int f = threadIdx.x;  // 64
    float acc = 0.0f;
    for (int r = b; r < rows; r += nb0) acc += c.P[(size_t)r * 64 + f];
    c.P2[b * 64 + f] = acc;
}

// single-wave FC: reduce 256 partial rows, then out = fcb + (S/n) @ fcw^T
__global__ void k_fc(Ctx c0, Ctx c1, const float* __restrict__ fcw,
                     const float* __restrict__ fcb, int n) {
    Ctx c = blockIdx.x ? c1 : c0;
    __shared__ float S[64];
    int j = threadIdx.x;  // 64
    float s = 0.0f;
    for (int r = 0; r < 256; ++r) s += c.P2[r * 64 + j];
    S[j] = s;
    __syncthreads();
    float inv = 1.0f / (float)n;
    float acc = fcb[j];
#pragma unroll
    for (int k = 0; k < 64; ++k) acc += (S[k] * inv) * fcw[j * 64 + k];
    c.outp[j] = acc;
}

extern "C" void kernel_launch(void* const* d_in, const int* in_sizes, int n_in,
                              void* d_out, int out_size, void* d_ws, size_t ws_size,
                              hipStream_t stream) {
    const float* x[2]  = {(const float*)d_in[0], (const float*)d_in[1]};
    const int*   ei[2] = {(const int*)d_in[2], (const int*)d_in[3]};
    const float* W1  = (const float*)d_in[4];
    const float* b1  = (const float*)d_in[5];
    const float* W2  = (const float*)d_in[6];
    const float* b2  = (const float*)d_in[7];
    const float* fcw = (const float*)d_in[8];
    const float* fcb = (const float*)d_in[9];
    float* out = (float*)d_out;

    const int N  = in_sizes[0] / 64;
    const int E  = in_sizes[2] / 2;
    const int NF = N * 64;
    const int K  = (N + CHUNK - 1) / CHUNK;     // 782 buckets
    const int gGm = (N + 7) / 8;                // aggregate blocks (8 nodes each)
    const int nTiles = (N + 15) / 16;
    const int gMf = (nTiles + 3) / 4;
    const int gBin = (E + EPB - 1) / EPB;
    const int gK  = (K + TPB - 1) / TPB;

    auto al = [](size_t x) { return (x + 127) & ~(size_t)127; };
    size_t tempB = (size_t)K * CAP * 4;
    size_t abB   = ((size_t)NF + 64) * 2;
    size_t szRegion = al(tempB > abB ? tempB : abB);   // Ab aliases temp
    size_t szHs  = al((size_t)NF + 64);                // fp8 + sentinel row N
    size_t szCsr = al((size_t)E * 4);
    size_t szRp  = al((size_t)(N + 1) * 4);
    size_t szDi  = al((size_t)N * 4);
    size_t szCu  = al((size_t)K * CPAD * 4);           // padded cursors
    size_t szBB  = al((size_t)K * 4);
    size_t szP   = al((size_t)gGm * 64 * 4);
    size_t szP2  = al((size_t)256 * 64 * 4);
    size_t setB  = szRegion + szHs + szCsr + szRp + szDi + szCu + szBB + szP + szP2;
    size_t wtB   = 2 * al(64 * 64 * 2);
    bool batched = ws_size >= wtB + 2 * setB;

    char* base = (char*)d_ws;
    unsigned short* Wt1 = (unsigned short*)base;
    unsigned short* Wt2 = (unsigned short*)(base + al(64 * 64 * 2));

    auto mkctx = [&](int g, char* p) {
        Ctx c;
        c.X = x[g]; c.esrc = ei[g]; c.edst = ei[g] + E;
        c.temp = (unsigned int*)p; c.Ab = (unsigned short*)p; p += szRegion;
        c.Hs = (unsigned char*)p; p += szHs;
        c.csr = (int*)p; p += szCsr;
        c.row_ptr = (int*)p; p += szRp;
        c.dinv = (float*)p; p += szDi;
        c.cursorG = (int*)p; p += szCu;
        c.bucketBase = (int*)p; p += szBB;
        c.P = (float*)p; p += szP;
        c.P2 = (float*)p;
        c.outp = out + g * 64;
        return c;
    };
    char* set0 = base + wtB;
    Ctx c0 = mkctx(0, set0);
    Ctx c1 = mkctx(1, batched ? set0 + setB : set0);   // fallback: shares set0

    k_prepW2<<<2, 256, 0, stream>>>(W1, W2, Wt1, Wt2);

    auto pipe = [&](Ctx A, Ctx B, int mult) {
        int swz = (mult == 2 && (gGm & 3) == 0) ? 1 : 0;
        k_zeroCur<<<mult * gK, TPB, 0, stream>>>(A, B, gK, K, N);
        k_binA<<<mult * gBin, 1024, 0, stream>>>(A, B, gBin, E, K);
        k_scanK<<<mult, 1024, 0, stream>>>(A, B, K, N, E);
        k_csrb<<<mult * K, 256, 0, stream>>>(A, B, K, N);
        k_gemm1<<<mult * gMf, 256, 0, stream>>>(A, B, gMf, Wt1, nTiles, N);
        k_agg1<<<mult * gGm, 256, 0, stream>>>(A, B, gGm, swz, b1, N);
        k_gemm2<<<mult * gMf, 256, 0, stream>>>(A, B, gMf, Wt2, nTiles, N);
        k_agg2<<<mult * gGm, 256, 0, stream>>>(A, B, gGm, swz, b2, N);
        k_colsum<<<mult * 256, 64, 0, stream>>>(A, B, 256, gGm);
        k_fc<<<mult, 64, 0, stream>>>(A, B, fcw, fcb, N);
    };

    if (batched) {
        pipe(c0, c1, 2);
    } else {
        pipe(c0, c0, 1);   // sequential, shared buffer set
        pipe(c1, c1, 1);
    }
}

// Round 19
// 311.636 us; speedup vs baseline: 1.4015x; 1.0293x over previous
//
#include <hip/hip_runtime.h>

// SiameseGNN round 19: pre-shifted CSR (saddr gathers) + scanK eliminated.
//
// R18 evidence: agg VALU ~42M wave-instrs vs ~6.4M intrinsic unpack+add --
// bulk is per-gather address math (shfl'd index -> <<6 -> 64-bit add ~3 ops).
//   fix 1: csr stores src<<6 (byte offset, low 6 bits free). Gather offset
//          = su | (s*4): 1 v_or; load uses SGPR-base + 32-bit voffset form.
//   fix 2: csr bucket-major with stride CAP (beg = b*CAP + lofs), explicit
//          deg[] array -> k_scanK (global bucket scan) deleted, one fewer
//          serial dispatch; csrb drops bucketBase.
// Everything else unchanged from R18 (sentinel row, 8-deep bursts, fp8,
// LDS-sort binA at 1024 threads, batching, XCD swizzle).

#define TPB    256
#define CHUNK  128
#define SHIFT  7
#define KMAX   1024
#define CAP    2560
#define EPB    8192
#define CPAD   16      // cursorG stride (ints)

typedef __attribute__((ext_vector_type(8))) short short8;
typedef __attribute__((ext_vector_type(4))) float f32x4;
typedef __attribute__((ext_vector_type(2))) float float2v;

struct Ctx {
    const float* X; const int* esrc; const int* edst;
    unsigned int* temp; unsigned short* Ab; unsigned char* Hs;
    unsigned int* csr; int* row_ptr; int* degA; float* dinv; int* cursorG;
    float* P; float* P2; float* outp;
};

__device__ __forceinline__ unsigned short f2bf(float x) {
    union { float f; unsigned int i; } c; c.f = x;
    unsigned int r = c.i + 0x7FFFu + ((c.i >> 16) & 1u);   // RNE
    return (unsigned short)(r >> 16);
}
__device__ __forceinline__ unsigned char f2fp8(float x) {
    int p = __builtin_amdgcn_cvt_pk_fp8_f32(x, x, 0, false);
    return (unsigned char)(p & 0xFF);
}
__device__ __forceinline__ float2v up8lo(unsigned int w) {
    return __builtin_amdgcn_cvt_pk_f32_fp8(w, false);
}
__device__ __forceinline__ float2v up8hi(unsigned int w) {
    return __builtin_amdgcn_cvt_pk_f32_fp8(w, true);
}

__global__ void k_prepW2(const float* __restrict__ W1, const float* __restrict__ W2,
                         unsigned short* __restrict__ Wt1, unsigned short* __restrict__ Wt2) {
    const float* W = blockIdx.x ? W2 : W1;
    unsigned short* Wt = blockIdx.x ? Wt2 : Wt1;
    for (int i = threadIdx.x; i < 64 * 64; i += 256) {
        int n = i >> 6, k = i & 63;
        Wt[i] = f2bf(W[k * 64 + n]);
    }
}

// zero cursors + zero the Hs sentinel row (row N; ws re-poisoned per call)
__global__ void k_zeroCur(Ctx c0, Ctx c1, int nb0, int K, int N) {
    int b = blockIdx.x; Ctx c = c0;
    if (b >= nb0) { c = c1; b -= nb0; }
    int i = b * blockDim.x + threadIdx.x;
    if (i < K) c.cursorG[i * CPAD] = 0;
    if (b == 0 && threadIdx.x < 64) c.Hs[(size_t)N * 64 + threadIdx.x] = 0;
}

// binA: LDS counting sort per block, burst segment writes. 1024 threads.
__global__ __launch_bounds__(1024) void k_binA(Ctx c0, Ctx c1, int nb0, int E, int K) {
    __shared__ int cnt[KMAX];
    __shared__ int ofs[KMAX];
    __shared__ int segBase[KMAX];
    __shared__ unsigned int sorted[EPB];
    __shared__ unsigned short bkt[EPB];
    int b = blockIdx.x; Ctx c = c0;
    if (b >= nb0) { c = c1; b -= nb0; }
    int tid = threadIdx.x;               // 0..1023 == KMAX
    cnt[tid] = 0;
    __syncthreads();
    int base = b * EPB;
    int tot = E - base; if (tot > EPB) tot = EPB;
#pragma unroll
    for (int k = 0; k < EPB / 1024; ++k) {
        int e = base + k * 1024 + tid;
        if (e < E) atomicAdd(&cnt[c.edst[e] >> SHIFT], 1);
    }
    __syncthreads();
    int v = cnt[tid];
    segBase[tid] = v;
    __syncthreads();
#pragma unroll
    for (int off = 1; off < 1024; off <<= 1) {
        int t = (tid >= off) ? segBase[tid - off] : 0;
        __syncthreads();
        segBase[tid] += t;
        __syncthreads();
    }
    ofs[tid] = segBase[tid] - v;
    __syncthreads();
    if (tid < K) {
        segBase[tid] = v ? atomicAdd(&c.cursorG[tid * CPAD], v) : 0;
    } else {
        segBase[tid] = 0;
    }
    cnt[tid] = 0;
    __syncthreads();
#pragma unroll
    for (int k = 0; k < EPB / 1024; ++k) {
        int e = base + k * 1024 + tid;
        if (e < E) {
            int d = c.edst[e];
            int bk = d >> SHIFT;
            int r = atomicAdd(&cnt[bk], 1);
            int p = ofs[bk] + r;
            sorted[p] = ((unsigned int)(d & (CHUNK - 1)) << 17) | (unsigned int)c.esrc[e];
            bkt[p] = (unsigned short)bk;
        }
    }
    __syncthreads();
    for (int p = tid; p < tot; p += 1024) {
        unsigned int vv = sorted[p];
        int bk = bkt[p];
        int pos = segBase[bk] + (p - ofs[bk]);
        if (pos < CAP) c.temp[(size_t)bk * CAP + pos] = vv;
    }
}

// Per-bucket LDS counting sort -> bucket-major csr slice (stride CAP) +
// row_ptr (beg) + deg + dinv. csr stores src<<6 (pre-shifted byte offset).
__global__ __launch_bounds__(256) void k_csrb(Ctx c0, Ctx c1, int nb0, int N) {
    __shared__ int deg[CHUNK];
    __shared__ int lofs[CHUNK];
    __shared__ int cur[CHUNK];
    int b = blockIdx.x; Ctx c = c0;
    if (b >= nb0) { c = c1; b -= nb0; }
    int tid = threadIdx.x;
    if (tid < CHUNK) deg[tid] = 0;
    __syncthreads();
    int cnt = c.cursorG[b * CPAD]; if (cnt > CAP) cnt = CAP;
    const size_t tb = (size_t)b * CAP;
    for (int i = tid; i < cnt; i += 256) atomicAdd(&deg[c.temp[tb + i] >> 17], 1);
    __syncthreads();
    if (tid < CHUNK) lofs[tid] = deg[tid];
    __syncthreads();
#pragma unroll
    for (int off = 1; off < CHUNK; off <<= 1) {
        int t = (tid < CHUNK && tid >= off) ? lofs[tid - off] : 0;
        __syncthreads();
        if (tid < CHUNK) lofs[tid] += t;
        __syncthreads();
    }
    int base = b * CAP;                  // bucket-major: no global scan needed
    if (tid < CHUNK) {
        int excl = lofs[tid] - deg[tid];
        lofs[tid] = excl;
        cur[tid] = 0;
        int node = b * CHUNK + tid;
        if (node < N) {
            c.row_ptr[node] = base + excl;
            c.degA[node] = deg[tid];
            c.dinv[node] = rsqrtf((float)deg[tid] + 1.0f);
        }
    }
    __syncthreads();
    for (int i = tid; i < cnt; i += 256) {
        unsigned int p = c.temp[tb + i];
        int dl = p >> 17;
        int rank = atomicAdd(&cur[dl], 1);
        c.csr[base + lofs[dl] + rank] = (p & 0x1FFFFu) << 6;   // src byte offset
    }
}

// Shared MFMA body: A-fragments provided; B from Wt; store fp8 Hs.
__device__ __forceinline__ void mfma_tail(short8 a0, short8 a1,
                                          const unsigned short* __restrict__ Wt,
                                          unsigned char* __restrict__ Hs,
                                          int row0, int r, int q, int N) {
    short8 bfrag[4][2];
#pragma unroll
    for (int ct = 0; ct < 4; ++ct)
#pragma unroll
        for (int kb = 0; kb < 2; ++kb)
            bfrag[ct][kb] = *(const short8*)(Wt + (ct * 16 + r) * 64 + q * 8 + 32 * kb);
    f32x4 acc[4];
#pragma unroll
    for (int ct = 0; ct < 4; ++ct) {
        acc[ct] = (f32x4){0.0f, 0.0f, 0.0f, 0.0f};
        acc[ct] = __builtin_amdgcn_mfma_f32_16x16x32_bf16(a0, bfrag[ct][0], acc[ct], 0, 0, 0);
        acc[ct] = __builtin_amdgcn_mfma_f32_16x16x32_bf16(a1, bfrag[ct][1], acc[ct], 0, 0, 0);
    }
#pragma unroll
    for (int reg = 0; reg < 4; ++reg) {
        int row = row0 + q * 4 + reg;
        if (row < N) {
            size_t base = (size_t)row * 64 + r;
#pragma unroll
            for (int ct = 0; ct < 4; ++ct)
                Hs[base + ct * 16] = f2fp8(acc[ct][reg]);
        }
    }
}

// GEMM1: fp32 X in, dinv folded into A-fragment conversion.
__global__ __launch_bounds__(256) void k_gemm1(Ctx c0, Ctx c1, int nb0,
                                               const unsigned short* __restrict__ Wt,
                                               int nTiles, int N) {
    int b = blockIdx.x; Ctx c = c0;
    if (b >= nb0) { c = c1; b -= nb0; }
    int wave = threadIdx.x >> 6, lane = threadIdx.x & 63;
    int tile = b * 4 + wave;
    if (tile >= nTiles) return;
    int r = lane & 15, q = lane >> 4;
    int row0 = tile * 16;
    int row = row0 + r;
    int rr = row < N ? row : N - 1;
    float d = c.dinv[rr];
    const float* xrow = c.X + (size_t)rr * 64 + q * 8;
    short8 a0, a1;
#pragma unroll
    for (int j = 0; j < 8; ++j) a0[j] = (short)f2bf(xrow[j] * d);
#pragma unroll
    for (int j = 0; j < 8; ++j) a1[j] = (short)f2bf(xrow[32 + j] * d);
    mfma_tail(a0, a1, Wt, c.Hs, row0, r, q, N);
}

// GEMM2: bf16 Ab in (already dinv-scaled by aggregate1).
__global__ __launch_bounds__(256) void k_gemm2(Ctx c0, Ctx c1, int nb0,
                                               const unsigned short* __restrict__ Wt,
                                               int nTiles, int N) {
    int b = blockIdx.x; Ctx c = c0;
    if (b >= nb0) { c = c1; b -= nb0; }
    int wave = threadIdx.x >> 6, lane = threadIdx.x & 63;
    int tile = b * 4 + wave;
    if (tile >= nTiles) return;
    int r = lane & 15, q = lane >> 4;
    int row0 = tile * 16;
    const unsigned short* xrow = c.Ab + (size_t)(row0 + r) * 64 + q * 8;
    short8 a0 = *(const short8*)(xrow);
    short8 a1 = *(const short8*)(xrow + 32);
    mfma_tail(a0, a1, Wt, c.Hs, row0, r, q, N);
}

// agg block mapping: XCD-partition swizzle (graph = (blockIdx>>2)&1) when
// swz, else linear split.
__device__ __forceinline__ void agg_map(int bi, int nb0, int swz,
                                        const Ctx& c0, const Ctx& c1,
                                        Ctx& c, int& b) {
    if (swz) {
        int graph = (bi >> 2) & 1;
        b = ((bi >> 3) << 2) | (bi & 3);
        c = graph ? c1 : c0;
    } else {
        b = bi; c = c0;
        if (b >= nb0) { c = c1; b -= nb0; }
    }
}

// 2 nodes per wave; per half: 2 groups x 16 lanes, lane s covers fp8
// channels 4s..4s+3. csr holds src<<6; gather offset = su | (s*4) -- one
// v_or, SGPR-base + voffset load. Invalid slots -> sentinel N<<6 (zeros).
__device__ __forceinline__ void agg_node2(const unsigned char* __restrict__ Hs,
                                          const unsigned int* __restrict__ csr,
                                          int beg, int deg, int maxd, int lane,
                                          unsigned int sent, float2v* acc) {
    int hbase = lane & 32;
    int hl = lane & 31;
    int g = (lane >> 4) & 1;
    unsigned int s4 = (unsigned int)((lane & 15) * 4);
    for (int base = 0; base < maxd; base += 32) {
        unsigned int idx = (base + hl < deg) ? csr[beg + base + hl] : sent;
        int mW = maxd - base; if (mW > 32) mW = 32;                 // wave-uniform
        for (int t = 0; t < mW; t += 16) {                          // 16-edge burst
            unsigned int h[8];
#pragma unroll
            for (int u = 0; u < 8; ++u) {                           // issue phase
                int slot = t + 2 * u + g;                           // <= 31
                unsigned int su = (unsigned int)__shfl((int)idx, hbase + slot, 64);
                h[u] = *(const unsigned int*)(Hs + (su | s4));      // saddr + voffset
            }
#pragma unroll
            for (int u = 0; u < 8; ++u) {                           // consume phase
                acc[0] += up8lo(h[u]); acc[1] += up8hi(h[u]);       // sentinel adds 0
            }
        }
    }
    // merge the half's 2 groups (bit 4); does not cross halves
#pragma unroll
    for (int k = 0; k < 2; ++k) {
        float2v o;
        o.x = __shfl_xor(acc[k].x, 16, 64); o.y = __shfl_xor(acc[k].y, 16, 64);
        acc[k] += o;
    }
}

// layer-1: Ab[d, f] = bf16( dinv[d] * relu(b[f] + dinv[d] * agg) )
__global__ __launch_bounds__(256) void k_agg1(Ctx c0, Ctx c1, int nb0, int swz,
                                              const float* __restrict__ bias, int n) {
    Ctx c; int b;
    agg_map(blockIdx.x, nb0, swz, c0, c1, c, b);
    int wave = threadIdx.x >> 6, lane = threadIdx.x & 63;
    int h = lane >> 5;
    int node = b * 8 + wave * 2 + h;
    int nd = node < n ? node : 0;
    int beg = c.row_ptr[nd];
    int deg = (node < n) ? c.degA[nd] : 0;
    int od = __shfl_xor(deg, 32, 64);
    int maxd = deg > od ? deg : od;      // wave-uniform
    float2v acc[2] = {{0.f, 0.f}, {0.f, 0.f}};
    agg_node2(c.Hs, c.csr, beg, deg, maxd, lane, (unsigned int)n << 6, acc);
    if (((lane >> 4) & 1) == 0 && node < n) {
        int s = lane & 15;
        unsigned int hv = *(const unsigned int*)(c.Hs + (size_t)node * 64 + s * 4);
        float2v h0 = up8lo(hv), h1 = up8hi(hv);
        float4 bb = *(const float4*)(bias + s * 4);
        float d = c.dinv[node];
        float v0 = fmaxf(bb.x + d * (acc[0].x + h0.x), 0.0f) * d;
        float v1 = fmaxf(bb.y + d * (acc[0].y + h0.y), 0.0f) * d;
        float v2 = fmaxf(bb.z + d * (acc[1].x + h1.x), 0.0f) * d;
        float v3 = fmaxf(bb.w + d * (acc[1].y + h1.y), 0.0f) * d;
        ushort4 o;
        o.x = f2bf(v0); o.y = f2bf(v1); o.z = f2bf(v2); o.w = f2bf(v3);
        *(ushort4*)(c.Ab + (size_t)node * 64 + s * 4) = o;
    }
}

// layer-2: block-reduce 8 relu'd rows -> P[block, f]
__global__ __launch_bounds__(256) void k_agg2(Ctx c0, Ctx c1, int nb0, int swz,
                                              const float* __restrict__ bias, int n) {
    __shared__ float red[8 * 64];
    Ctx c; int b;
    agg_map(blockIdx.x, nb0, swz, c0, c1, c, b);
    int wave = threadIdx.x >> 6, lane = threadIdx.x & 63;
    int h = lane >> 5;
    int node = b * 8 + wave * 2 + h;
    int nd = node < n ? node : 0;
    int beg = c.row_ptr[nd];
    int deg = (node < n) ? c.degA[nd] : 0;
    int od = __shfl_xor(deg, 32, 64);
    int maxd = deg > od ? deg : od;
    float2v acc[2] = {{0.f, 0.f}, {0.f, 0.f}};
    agg_node2(c.Hs, c.csr, beg, deg, maxd, lane, (unsigned int)n << 6, acc);
    if (((lane >> 4) & 1) == 0) {
        int s = lane & 15;
        float4 v = {0.f, 0.f, 0.f, 0.f};
        if (node < n) {
            unsigned int hv = *(const unsigned int*)(c.Hs + (size_t)node * 64 + s * 4);
            float2v h0 = up8lo(hv), h1 = up8hi(hv);
            float4 bb = *(const float4*)(bias + s * 4);
            float d = c.dinv[node];
            v.x = fmaxf(bb.x + d * (acc[0].x + h0.x), 0.0f);
            v.y = fmaxf(bb.y + d * (acc[0].y + h0.y), 0.0f);
            v.z = fmaxf(bb.z + d * (acc[1].x + h1.x), 0.0f);
            v.w = fmaxf(bb.w + d * (acc[1].y + h1.y), 0.0f);
        }
        *(float4*)(&red[(wave * 2 + h) * 64 + s * 4]) = v;
    }
    __syncthreads();
    if (threadIdx.x < 64) {
        float acc8 = 0.0f;
#pragma unroll
        for (int r = 0; r < 8; ++r) acc8 += red[r * 64 + threadIdx.x];
        c.P[(size_t)b * 64 + threadIdx.x] = acc8;
    }
}

// colsum -> per-block partials in P2 (no atomics, no zero pass)
__global__ void k_colsum(Ctx c0, Ctx c1, int nb0, int rows) {
    int b = blockIdx.x; Ctx c = c0;
    if (b >= nb0) { c = c1; b -= nb0; }
    int f = threadIdx.x;  // 64
    float acc = 0.0f;
    for (int r = b; r < rows; r += nb0) acc += c.P[(size_t)r * 64 + f];
    c.P2[b * 64 + f] = acc;
}

// single-wave FC: reduce 256 partial rows, then out = fcb + (S/n) @ fcw^T
__global__ void k_fc(Ctx c0, Ctx c1, const float* __restrict__ fcw,
                     const float* __restrict__ fcb, int n) {
    Ctx c = blockIdx.x ? c1 : c0;
    __shared__ float S[64];
    int j = threadIdx.x;  // 64
    float s = 0.0f;
    for (int r = 0; r < 256; ++r) s += c.P2[r * 64 + j];
    S[j] = s;
    __syncthreads();
    float inv = 1.0f / (float)n;
    float acc = fcb[j];
#pragma unroll
    for (int k = 0; k < 64; ++k) acc += (S[k] * inv) * fcw[j * 64 + k];
    c.outp[j] = acc;
}

extern "C" void kernel_launch(void* const* d_in, const int* in_sizes, int n_in,
                              void* d_out, int out_size, void* d_ws, size_t ws_size,
                              hipStream_t stream) {
    const float* x[2]  = {(const float*)d_in[0], (const float*)d_in[1]};
    const int*   ei[2] = {(const int*)d_in[2], (const int*)d_in[3]};
    const float* W1  = (const float*)d_in[4];
    const float* b1  = (const float*)d_in[5];
    const float* W2  = (const float*)d_in[6];
    const float* b2  = (const float*)d_in[7];
    const float* fcw = (const float*)d_in[8];
    const float* fcb = (const float*)d_in[9];
    float* out = (float*)d_out;

    const int N  = in_sizes[0] / 64;
    const int E  = in_sizes[2] / 2;
    const int NF = N * 64;
    const int K  = (N + CHUNK - 1) / CHUNK;     // 782 buckets
    const int gGm = (N + 7) / 8;                // aggregate blocks (8 nodes each)
    const int nTiles = (N + 15) / 16;
    const int gMf = (nTiles + 3) / 4;
    const int gBin = (E + EPB - 1) / EPB;
    const int gK  = (K + TPB - 1) / TPB;

    auto al = [](size_t x) { return (x + 127) & ~(size_t)127; };
    size_t tempB = (size_t)K * CAP * 4;
    size_t abB   = ((size_t)NF + 64) * 2;
    size_t szRegion = al(tempB > abB ? tempB : abB);   // Ab aliases temp
    size_t szHs  = al((size_t)NF + 64);                // fp8 + sentinel row N
    size_t szCsr = al((size_t)K * CAP * 4);            // bucket-major, stride CAP
    size_t szRp  = al((size_t)N * 4);                  // beg only
    size_t szDeg = al((size_t)N * 4);
    size_t szDi  = al((size_t)N * 4);
    size_t szCu  = al((size_t)K * CPAD * 4);           // padded cursors
    size_t szP   = al((size_t)gGm * 64 * 4);
    size_t szP2  = al((size_t)256 * 64 * 4);
    size_t setB  = szRegion + szHs + szCsr + szRp + szDeg + szDi + szCu + szP + szP2;
    size_t wtB   = 2 * al(64 * 64 * 2);
    bool batched = ws_size >= wtB + 2 * setB;

    char* base = (char*)d_ws;
    unsigned short* Wt1 = (unsigned short*)base;
    unsigned short* Wt2 = (unsigned short*)(base + al(64 * 64 * 2));

    auto mkctx = [&](int g, char* p) {
        Ctx c;
        c.X = x[g]; c.esrc = ei[g]; c.edst = ei[g] + E;
        c.temp = (unsigned int*)p; c.Ab = (unsigned short*)p; p += szRegion;
        c.Hs = (unsigned char*)p; p += szHs;
        c.csr = (unsigned int*)p; p += szCsr;
        c.row_ptr = (int*)p; p += szRp;
        c.degA = (int*)p; p += szDeg;
        c.dinv = (float*)p; p += szDi;
        c.cursorG = (int*)p; p += szCu;
        c.P = (float*)p; p += szP;
        c.P2 = (float*)p;
        c.outp = out + g * 64;
        return c;
    };
    char* set0 = base + wtB;
    Ctx c0 = mkctx(0, set0);
    Ctx c1 = mkctx(1, batched ? set0 + setB : set0);   // fallback: shares set0

    k_prepW2<<<2, 256, 0, stream>>>(W1, W2, Wt1, Wt2);

    auto pipe = [&](Ctx A, Ctx B, int mult) {
        int swz = (mult == 2 && (gGm & 3) == 0) ? 1 : 0;
        k_zeroCur<<<mult * gK, TPB, 0, stream>>>(A, B, gK, K, N);
        k_binA<<<mult * gBin, 1024, 0, stream>>>(A, B, gBin, E, K);
        k_csrb<<<mult * K, 256, 0, stream>>>(A, B, K, N);
        k_gemm1<<<mult * gMf, 256, 0, stream>>>(A, B, gMf, Wt1, nTiles, N);
        k_agg1<<<mult * gGm, 256, 0, stream>>>(A, B, gGm, swz, b1, N);
        k_gemm2<<<mult * gMf, 256, 0, stream>>>(A, B, gMf, Wt2, nTiles, N);
        k_agg2<<<mult * gGm, 256, 0, stream>>>(A, B, gGm, swz, b2, N);
        k_colsum<<<mult * 256, 64, 0, stream>>>(A, B, 256, gGm);
        k_fc<<<mult, 64, 0, stream>>>(A, B, fcw, fcb, N);
    };

    if (batched) {
        pipe(c0, c1, 2);
    } else {
        pipe(c0, c0, 1);   // sequential, shared buffer set
        pipe(c1, c1, 1);
    }
}